// Round 10
// baseline (145.057 us; speedup 1.0000x reference)
//
#include <hip/hip_runtime.h>
#include <math.h>

namespace {

constexpr int E_  = 768;
constexpr int H_  = 12;
constexpr int DH_ = 64;
constexpr int T_  = 2048;
constexpr int B_  = 2;
constexpr int M_  = B_ * T_;  // 4096
constexpr int BH_ = B_ * H_;  // 24
constexpr int NSPLIT = 4;     // attention k-range split factor

typedef __attribute__((ext_vector_type(8))) short bf16x8;
typedef __attribute__((ext_vector_type(4))) float f32x4;

union Frag { bf16x8 v; uint2 u[2]; unsigned w[4]; };

__device__ inline ushort f2bf(float f) {
  union { float f; unsigned u; } v; v.f = f;
  unsigned u = v.u + 0x7FFFu + ((v.u >> 16) & 1u);  // RNE
  return (ushort)(u >> 16);
}
__device__ inline float bf2f(ushort u) {
  union { unsigned u; float f; } v; v.u = (unsigned)u << 16; return v.f;
}

// async global->LDS, 16B per lane (wave-uniform LDS base, per-lane global src)
__device__ __forceinline__ void gl16(const ushort* g, ushort* l) {
  __builtin_amdgcn_global_load_lds(
      (const __attribute__((address_space(1))) unsigned int*)(g),
      (__attribute__((address_space(3))) unsigned int*)(l), 16, 0, 0);
}

// ---------------------------------------------------------------------------
// prep: blocks [0,1536) convert x f32->bf16; blocks [1536,2112) transpose W.
// ---------------------------------------------------------------------------
constexpr int NCONV = 1536;

__global__ __launch_bounds__(256) void prep_k(
    const float* __restrict__ x,
    const float* __restrict__ Wq, const float* __restrict__ Wk,
    const float* __restrict__ Wv, const float* __restrict__ Wp,
    ushort* __restrict__ xb, ushort* __restrict__ Wt, ushort* __restrict__ Wpt)
{
  __shared__ float tile[64][65];
  const int bid = blockIdx.x;
  const int tid = threadIdx.x;

  if (bid < NCONV) {
    const size_t i = ((size_t)bid * 256 + tid) * 8;
    float4 a = *(const float4*)(x + i);
    float4 b = *(const float4*)(x + i + 4);
    ushort o[8] = {f2bf(a.x), f2bf(a.y), f2bf(a.z), f2bf(a.w),
                   f2bf(b.x), f2bf(b.y), f2bf(b.z), f2bf(b.w)};
    *(bf16x8*)(xb + i) = *(bf16x8*)o;
    return;
  }

  const int wb = bid - NCONV;  // 0..575
  const int tr = tid >> 4, tc = tid & 15;
  const float* src; ushort* dst;
  int k0, n0, sN, dK;
  if (wb < 432) {
    const int mat = wb / 144, rem = wb % 144;
    const int h = rem / 12, ktile = rem % 12;
    const float* W = (mat == 0) ? Wq : (mat == 1) ? Wk : Wv;
    src = W + (size_t)h * E_ * DH_;
    dst = Wt + (size_t)(mat * H_ + h) * DH_ * E_;
    k0 = ktile * 64; n0 = 0; sN = DH_; dK = E_;
  } else {
    const int rem = wb - 432;
    src = Wp;
    dst = Wpt;
    k0 = (rem / 12) * 64; n0 = (rem % 12) * 64; sN = E_; dK = E_;
  }

#pragma unroll
  for (int rr = 0; rr < 64; rr += 16) {
    float4 v = *(const float4*)(src + (size_t)(k0 + tr + rr) * sN + n0 + tc * 4);
    tile[tr + rr][tc * 4 + 0] = v.x;
    tile[tr + rr][tc * 4 + 1] = v.y;
    tile[tr + rr][tc * 4 + 2] = v.z;
    tile[tr + rr][tc * 4 + 3] = v.w;
  }
  __syncthreads();
#pragma unroll
  for (int rr = 0; rr < 64; rr += 16) {
    const int n = tr + rr;
    ushort4 o;
    o.x = f2bf(tile[tc * 4 + 0][n]);
    o.y = f2bf(tile[tc * 4 + 1][n]);
    o.z = f2bf(tile[tc * 4 + 2][n]);
    o.w = f2bf(tile[tc * 4 + 3][n]);
    *(ushort4*)(dst + (size_t)(n0 + n) * dK + k0 + tc * 4) = o;
  }
}

// ---------------------------------------------------------------------------
// QKV GEMM: 128x64 tiles (unchanged from R9).
// ---------------------------------------------------------------------------
constexpr float QSCALE = 0.18033688f;  // 1/8 * log2(e)

__global__ __launch_bounds__(256) void qkv_fused_k(
    const ushort* __restrict__ xb, const ushort* __restrict__ Wt,
    ushort* __restrict__ q_ws, ushort* __restrict__ k_ws, ushort* __restrict__ vt_ws)
{
  __shared__ __align__(16) ushort lds[(128 + 64) * 64];  // As | Bs (24 KB)
  ushort* As = lds;
  ushort* Bs = lds + 128 * 64;

  const int seg = blockIdx.x;        // 0..35: (mat, head)
  const int m0  = blockIdx.y * 128;
  const ushort* Wh = Wt + (size_t)seg * DH_ * E_;

  const int tid  = threadIdx.x;
  const int w    = tid >> 6, l = tid & 63;
  const int lrow = l & 15, lk = l >> 4;
  const int r7   = lrow & 7;
  const int srow = l >> 3;
  const int sch  = (l & 7) ^ srow;

  f32x4 acc[2][4] = {};

  for (int k0 = 0; k0 < E_; k0 += 64) {
#pragma unroll
    for (int r = 0; r < 4; ++r) {
      const int base = r * 32 + w * 8;
      gl16(xb + (size_t)(m0 + base + srow) * E_ + k0 + sch * 8, &As[base * 64]);
      if (r < 2)
        gl16(Wh + (size_t)(base + srow) * E_ + k0 + sch * 8, &Bs[base * 64]);
    }
    __syncthreads();

#pragma unroll
    for (int kk = 0; kk < 2; ++kk) {
      const int cof = ((kk * 4 + lk) ^ r7) * 8;
      const bf16x8 a0 = *(const bf16x8*)&As[(w * 32 + lrow) * 64 + cof];
      const bf16x8 a1 = *(const bf16x8*)&As[(w * 32 + 16 + lrow) * 64 + cof];
#pragma unroll
      for (int nf = 0; nf < 4; ++nf) {
        const bf16x8 b = *(const bf16x8*)&Bs[(nf * 16 + lrow) * 64 + cof];
        acc[0][nf] = __builtin_amdgcn_mfma_f32_16x16x32_bf16(a0, b, acc[0][nf], 0, 0, 0);
        acc[1][nf] = __builtin_amdgcn_mfma_f32_16x16x32_bf16(a1, b, acc[1][nf], 0, 0, 0);
      }
    }
    __syncthreads();
  }

  const int b   = m0 >> 11;
  const int t0  = m0 & 2047;
  const int mat = seg / H_;
  const int h   = seg - mat * H_;
  const int bh  = b * H_ + h;

  if (mat != 2) {
    const float qs = (mat == 0) ? QSCALE : 1.0f;
    ushort* outw = (mat == 0) ? q_ws : k_ws;
#pragma unroll
    for (int mi = 0; mi < 2; ++mi)
#pragma unroll
      for (int i = 0; i < 4; ++i) {
        const int t = t0 + w * 32 + mi * 16 + lk * 4 + i;
        ushort* orow = outw + ((size_t)bh * T_ + t) * DH_;
#pragma unroll
        for (int nf = 0; nf < 4; ++nf)
          orow[nf * 16 + lrow] = f2bf(acc[mi][nf][i] * qs);
      }
  } else {
    ushort* Td = lds;  // [64][136]
    __syncthreads();
#pragma unroll
    for (int mi = 0; mi < 2; ++mi)
#pragma unroll
      for (int i = 0; i < 4; ++i) {
        const int tl = w * 32 + mi * 16 + lk * 4 + i;
#pragma unroll
        for (int nf = 0; nf < 4; ++nf)
          Td[(nf * 16 + lrow) * 136 + tl] = f2bf(acc[mi][nf][i]);
      }
    __syncthreads();
#pragma unroll
    for (int it = 0; it < 4; ++it) {
      const int c = tid + it * 256;
      const int d = c >> 4, sub = c & 15;
      *(bf16x8*)(vt_ws + ((size_t)bh * DH_ + d) * T_ + t0 + sub * 8) =
          *(const bf16x8*)&Td[d * 136 + sub * 8];
    }
  }
}

// ---------------------------------------------------------------------------
// Causal flash attention, split x4, IN-REGISTER P:
// PV computed as O^T = mfma(A=V^T frag, B=P^T frag) where B is exactly the
// S^T accumulator (after exp2/cvt_pk) -- MFMA k-slot permutation
// sigma(lk,j) = (j>>2)*16 + lk*4 + (j&3) applied consistently to the V^T
// A-read makes this algebraically exact. No P LDS, no P shuffles; m/l/corr
// are lane-uniform (q = lane&15). LDS = 16 KB (K,V only).
// ---------------------------------------------------------------------------
__global__ __launch_bounds__(256, 6) void attn_split_k(
    const ushort* __restrict__ q_ws, const ushort* __restrict__ k_ws,
    const ushort* __restrict__ vt_ws, ushort* __restrict__ op_ws,
    float2* __restrict__ ml_ws)
{
  __shared__ __align__(16) ushort Ks[64 * 64];   // K tile [s][e], swizzled
  __shared__ __align__(16) ushort Vt[64 * 64];   // V^T tile [d][s], swizzled

  const int qt = 31 - (int)blockIdx.y;
  const int bh = blockIdx.x;
  const int hz = blockIdx.z;               // 0..3
  const int nt = qt + 1;
  const int klo = (hz * nt) >> 2;
  const int khi = ((hz + 1) * nt) >> 2;
  const int q0 = qt * 64;

  const ushort* Qb  = q_ws + (size_t)bh * T_ * DH_;
  const ushort* Kb  = k_ws + (size_t)bh * T_ * DH_;
  const ushort* VTb = vt_ws + (size_t)bh * DH_ * T_;

  const int tid  = threadIdx.x;
  const int w    = tid >> 6;
  const int l    = tid & 63;
  const int lrow = l & 15;
  const int lk   = l >> 4;
  const int r7   = lrow & 7;
  const int rr   = tid >> 3;       // staging rows rr, rr+32
  const int sub  = tid & 7;
  const int swc  = sub ^ (rr & 7);

  const int st0 = rr * 64 + swc * 8;
  const int st1 = (rr + 32) * 64 + swc * 8;

  // K fragment read offsets (b128): row = ct*16+lrow, chunks lk, lk+4
  int kof0[4], kof1[4];
#pragma unroll
  for (int ct = 0; ct < 4; ++ct) {
    kof0[ct] = (ct * 16 + lrow) * 64 + ((lk ^ r7) * 8);
    kof1[ct] = (ct * 16 + lrow) * 64 + (((lk + 4) ^ r7) * 8);
  }
  // V^T A-operand b64 byte offsets (sigma permutation): col = q16*16 + lk*4
  int vof[4];
#pragma unroll
  for (int q16 = 0; q16 < 4; ++q16)
    vof[q16] = lrow * 128 + (((q16 * 2 + (lk >> 1)) ^ r7) << 4) + ((lk & 1) << 3);

  // Q fragment (B-operand of swapped QK^T): lane holds Q[q=lrow][e=lk*8+j]
  const ushort* Qrow = Qb + (size_t)(q0 + w * 16 + lrow) * DH_;
  const bf16x8 qa0 = *(const bf16x8*)(Qrow + lk * 8);
  const bf16x8 qa1 = *(const bf16x8*)(Qrow + lk * 8 + 32);
  const int qglob = q0 + w * 16 + lrow;

  float m_r = -INFINITY, l_r = 0.f;
  f32x4 oc[4] = {};   // oc[ct][i] = O^T[d = ct*16 + lk*4 + i][q = lrow]

  if (klo < khi) {
    bf16x8 kp0 = *(const bf16x8*)(Kb + (size_t)(klo * 64 + rr) * DH_ + sub * 8);
    bf16x8 kp1 = *(const bf16x8*)(Kb + (size_t)(klo * 64 + rr + 32) * DH_ + sub * 8);
    bf16x8 vp0 = *(const bf16x8*)(VTb + (size_t)rr * T_ + klo * 64 + sub * 8);
    bf16x8 vp1 = *(const bf16x8*)(VTb + (size_t)(rr + 32) * T_ + klo * 64 + sub * 8);

    for (int kt = klo; kt < khi; ++kt) {
      const int s0 = kt * 64;

      *(bf16x8*)&Ks[st0] = kp0;
      *(bf16x8*)&Ks[st1] = kp1;
      *(bf16x8*)&Vt[st0] = vp0;
      *(bf16x8*)&Vt[st1] = vp1;
      __syncthreads();

      if (kt + 1 < khi) {
        const int sn = s0 + 64;
        kp0 = *(const bf16x8*)(Kb + (size_t)(sn + rr) * DH_ + sub * 8);
        kp1 = *(const bf16x8*)(Kb + (size_t)(sn + rr + 32) * DH_ + sub * 8);
        vp0 = *(const bf16x8*)(VTb + (size_t)rr * T_ + sn + sub * 8);
        vp1 = *(const bf16x8*)(VTb + (size_t)(rr + 32) * T_ + sn + sub * 8);
      }

      // S^T = K Q^T : st[ct][i] -> s = s0+ct*16+lk*4+i, q = lrow
      f32x4 st[4];
#pragma unroll
      for (int ct = 0; ct < 4; ++ct) {
        const bf16x8 kb0 = *(const bf16x8*)&Ks[kof0[ct]];
        const bf16x8 kb1 = *(const bf16x8*)&Ks[kof1[ct]];
        f32x4 z = {0.f, 0.f, 0.f, 0.f};
        z = __builtin_amdgcn_mfma_f32_16x16x32_bf16(kb0, qa0, z, 0, 0, 0);
        st[ct] = __builtin_amdgcn_mfma_f32_16x16x32_bf16(kb1, qa1, z, 0, 0, 0);
      }

      if (kt == qt) {  // diagonal tile only
#pragma unroll
        for (int ct = 0; ct < 4; ++ct)
#pragma unroll
          for (int i = 0; i < 4; ++i)
            if (s0 + ct * 16 + lk * 4 + i > qglob) st[ct][i] = -INFINITY;
      }

      float mc[4];
#pragma unroll
      for (int ct = 0; ct < 4; ++ct)
        mc[ct] = fmaxf(fmaxf(st[ct][0], st[ct][1]), fmaxf(st[ct][2], st[ct][3]));
      float mx = fmaxf(fmaxf(mc[0], mc[1]), fmaxf(mc[2], mc[3]));
      mx = fmaxf(mx, __shfl_xor(mx, 16));
      mx = fmaxf(mx, __shfl_xor(mx, 32));

      // defer-max; corr is lane-uniform for q = lrow -> no shuffles
      if (__any(mx > m_r + 8.f)) {
        const float mn   = fmaxf(m_r, mx);
        const float corr = exp2f(m_r - mn);
        m_r = mn;
        l_r *= corr;
#pragma unroll
        for (int ct = 0; ct < 4; ++ct)
#pragma unroll
          for (int i = 0; i < 4; ++i) oc[ct][i] *= corr;
      }

      float sc[4];
#pragma unroll
      for (int ct = 0; ct < 4; ++ct) {
#pragma unroll
        for (int i = 0; i < 4; ++i) st[ct][i] = exp2f(st[ct][i] - m_r);
        sc[ct] = (st[ct][0] + st[ct][1]) + (st[ct][2] + st[ct][3]);
      }
      float rs = (sc[0] + sc[1]) + (sc[2] + sc[3]);
      rs += __shfl_xor(rs, 16);
      rs += __shfl_xor(rs, 32);
      l_r += rs;

      // P^T fragments IN REGISTERS (B-operand slots match S^T layout)
      Frag pb0, pb1;
      asm("v_cvt_pk_bf16_f32 %0, %1, %2" : "=v"(pb0.w[0]) : "v"(st[0][0]), "v"(st[0][1]));
      asm("v_cvt_pk_bf16_f32 %0, %1, %2" : "=v"(pb0.w[1]) : "v"(st[0][2]), "v"(st[0][3]));
      asm("v_cvt_pk_bf16_f32 %0, %1, %2" : "=v"(pb0.w[2]) : "v"(st[1][0]), "v"(st[1][1]));
      asm("v_cvt_pk_bf16_f32 %0, %1, %2" : "=v"(pb0.w[3]) : "v"(st[1][2]), "v"(st[1][3]));
      asm("v_cvt_pk_bf16_f32 %0, %1, %2" : "=v"(pb1.w[0]) : "v"(st[2][0]), "v"(st[2][1]));
      asm("v_cvt_pk_bf16_f32 %0, %1, %2" : "=v"(pb1.w[1]) : "v"(st[2][2]), "v"(st[2][3]));
      asm("v_cvt_pk_bf16_f32 %0, %1, %2" : "=v"(pb1.w[2]) : "v"(st[3][0]), "v"(st[3][1]));
      asm("v_cvt_pk_bf16_f32 %0, %1, %2" : "=v"(pb1.w[3]) : "v"(st[3][2]), "v"(st[3][3]));

      // O^T += V^T . P^T  (A-read applies sigma: cols q16*16 + lk*4)
#pragma unroll
      for (int ct = 0; ct < 4; ++ct) {
        const char* vb = (const char*)Vt + ct * 2048;
        Frag va0, va1;
        va0.u[0] = *(const uint2*)(vb + vof[0]);
        va0.u[1] = *(const uint2*)(vb + vof[1]);
        va1.u[0] = *(const uint2*)(vb + vof[2]);
        va1.u[1] = *(const uint2*)(vb + vof[3]);
        oc[ct] = __builtin_amdgcn_mfma_f32_16x16x32_bf16(va0.v, pb0.v, oc[ct], 0, 0, 0);
        oc[ct] = __builtin_amdgcn_mfma_f32_16x16x32_bf16(va1.v, pb1.v, oc[ct], 0, 0, 0);
      }
      __syncthreads();
    }
  }

  // epilogue: unnormalized O^T partial + per-row (m,l); all lane-uniform in q
  const size_t pb = (size_t)(hz * BH_ + bh) * T_;
  const int t = q0 + w * 16 + lrow;
  if (lk == 0)
    ml_ws[pb + t] = make_float2(m_r, l_r);
  ushort* orow = op_ws + (pb + t) * DH_;
#pragma unroll
  for (int ct = 0; ct < 4; ++ct) {
    ushort4 o4;
    o4.x = f2bf(oc[ct][0]); o4.y = f2bf(oc[ct][1]);
    o4.z = f2bf(oc[ct][2]); o4.w = f2bf(oc[ct][3]);
    *(ushort4*)(orow + ct * 16 + lk * 4) = o4;
  }
}

// ---------------------------------------------------------------------------
// Out-proj GEMM with fused 4-way split-k combine (64x64 tiles).
// ---------------------------------------------------------------------------
__global__ __launch_bounds__(256) void proj_fused_k(
    const ushort* __restrict__ op_ws, const float2* __restrict__ ml_ws,
    const ushort* __restrict__ Wpt, const float* __restrict__ bp,
    float* __restrict__ out)
{
  __shared__ __align__(16) ushort lds[(64 + 64) * 64];  // As | Bs (16 KB)
  ushort* As = lds;
  ushort* Bs = lds + 64 * 64;

  const int n0 = blockIdx.x * 64;
  const int m0 = blockIdx.y * 64;
  const int b  = m0 >> 11;
  const int t0 = m0 & 2047;

  const int tid  = threadIdx.x;
  const int w    = tid >> 6, l = tid & 63;
  const int lrow = l & 15, lk = l >> 4;
  const int r7   = lrow & 7;
  const int srow = l >> 3;
  const int sch  = (l & 7) ^ srow;
  const int ar = tid >> 2;          // A-staging row 0..63
  const int cc = tid & 3;           // 16-elem chunk
  const int a7 = ar & 7;

  f32x4 acc[4] = {};

  for (int k0 = 0; k0 < E_; k0 += 64) {
    const int h  = k0 >> 6;
    const int bh = b * H_ + h;

#pragma unroll
    for (int r = 0; r < 2; ++r) {
      const int base = r * 32 + w * 8;
      gl16(Wpt + (size_t)(n0 + base + srow) * E_ + k0 + sch * 8, &Bs[base * 64]);
    }

    // A staging: combine NSPLIT partials in regs, swizzled ds_write
    {
      const int t = t0 + ar;
      size_t ix[NSPLIT];
      float2 ml[NSPLIT];
#pragma unroll
      for (int z = 0; z < NSPLIT; ++z) {
        ix[z] = ((size_t)(z * BH_ + bh) * T_ + t);
        ml[z] = ml_ws[ix[z]];
      }
      float m = fmaxf(fmaxf(ml[0].x, ml[1].x), fmaxf(ml[2].x, ml[3].x));
      float f[NSPLIT];
      float den = 0.f;
#pragma unroll
      for (int z = 0; z < NSPLIT; ++z) {
        f[z] = exp2f(ml[z].x - m);
        den += f[z] * ml[z].y;
      }
      const float inv = 1.0f / den;
#pragma unroll
      for (int z = 0; z < NSPLIT; ++z) f[z] *= inv;

      float o[16] = {};
#pragma unroll
      for (int z = 0; z < NSPLIT; ++z) {
        const ushort* p = op_ws + ix[z] * DH_ + cc * 16;
        bf16x8 x0 = *(const bf16x8*)p;
        bf16x8 x1 = *(const bf16x8*)(p + 8);
#pragma unroll
        for (int j = 0; j < 8; ++j) {
          o[j]     += f[z] * bf2f((ushort)x0[j]);
          o[8 + j] += f[z] * bf2f((ushort)x1[j]);
        }
      }
      ushort ob[16];
#pragma unroll
      for (int j = 0; j < 16; ++j) ob[j] = f2bf(o[j]);
      *(bf16x8*)&As[ar * 64 + ((2 * cc) ^ a7) * 8]     = *(const bf16x8*)&ob[0];
      *(bf16x8*)&As[ar * 64 + ((2 * cc + 1) ^ a7) * 8] = *(const bf16x8*)&ob[8];
    }
    __syncthreads();

#pragma unroll
    for (int kk = 0; kk < 2; ++kk) {
      const int cof = ((kk * 4 + lk) ^ r7) * 8;
      const bf16x8 a = *(const bf16x8*)&As[(w * 16 + lrow) * 64 + cof];
#pragma unroll
      for (int nf = 0; nf < 4; ++nf) {
        const bf16x8 bb = *(const bf16x8*)&Bs[(nf * 16 + lrow) * 64 + cof];
        acc[nf] = __builtin_amdgcn_mfma_f32_16x16x32_bf16(a, bb, acc[nf], 0, 0, 0);
      }
    }
    __syncthreads();
  }

  float bias[4];
#pragma unroll
  for (int nf = 0; nf < 4; ++nf) bias[nf] = bp[n0 + nf * 16 + lrow];

#pragma unroll
  for (int i = 0; i < 4; ++i) {
    const int m = m0 + w * 16 + lk * 4 + i;
    float* orow = out + (size_t)m * E_ + n0;
#pragma unroll
    for (int nf = 0; nf < 4; ++nf)
      orow[nf * 16 + lrow] = acc[nf][i] + bias[nf];
  }
}

}  // namespace

extern "C" void kernel_launch(void* const* d_in, const int* in_sizes, int n_in,
                              void* d_out, int out_size, void* d_ws, size_t ws_size,
                              hipStream_t stream) {
  const float* x  = (const float*)d_in[0];
  const float* Wq = (const float*)d_in[1];
  const float* Wk = (const float*)d_in[2];
  const float* Wv = (const float*)d_in[3];
  const float* Wp = (const float*)d_in[4];
  const float* bp = (const float*)d_in[5];
  float* out = (float*)d_out;

  const size_t nx  = (size_t)M_ * E_;            // 3,145,728
  const size_t nwt = (size_t)3 * H_ * DH_ * E_;  // 1,769,472
  const size_t nwp = (size_t)E_ * E_;            // 589,824
  const size_t per = (size_t)BH_ * T_ * DH_;     // 3,145,728

  ushort* xb    = (ushort*)d_ws;
  ushort* Wt    = xb + nx;
  ushort* Wpt   = Wt + nwt;
  ushort* q_ws  = Wpt + nwp;
  ushort* k_ws  = q_ws + per;
  ushort* vt_ws = k_ws + per;     // [bh][d][t]
  ushort* op_ws = vt_ws + per;    // [NSPLIT][bh][t][64] partials
  float2* ml_ws = (float2*)(op_ws + NSPLIT * per);  // [NSPLIT][bh][t]

  prep_k<<<dim3(NCONV + 576), 256, 0, stream>>>(x, Wq, Wk, Wv, Wp, xb, Wt, Wpt);
  qkv_fused_k<<<dim3(36, 32), 256, 0, stream>>>(xb, Wt, q_ws, k_ws, vt_ws);
  attn_split_k<<<dim3(24, 32, NSPLIT), 256, 0, stream>>>(q_ws, k_ws, vt_ws, op_ws, ml_ws);
  proj_fused_k<<<dim3(12, 64), 256, 0, stream>>>(op_ws, ml_ws, Wpt, bp, out);
}

// Round 11
// 134.956 us; speedup vs baseline: 1.0748x; 1.0748x over previous
//
#include <hip/hip_runtime.h>
#include <math.h>

namespace {

constexpr int E_  = 768;
constexpr int H_  = 12;
constexpr int DH_ = 64;
constexpr int T_  = 2048;
constexpr int B_  = 2;
constexpr int M_  = B_ * T_;  // 4096
constexpr int BH_ = B_ * H_;  // 24
constexpr int NSPLIT = 2;     // attention k-range split factor (2: L2-safe, R8-verified)

typedef __attribute__((ext_vector_type(8))) short bf16x8;
typedef __attribute__((ext_vector_type(4))) float f32x4;

union Frag { bf16x8 v; uint2 u[2]; unsigned w[4]; };

__device__ inline ushort f2bf(float f) {
  union { float f; unsigned u; } v; v.f = f;
  unsigned u = v.u + 0x7FFFu + ((v.u >> 16) & 1u);  // RNE
  return (ushort)(u >> 16);
}
__device__ inline float bf2f(ushort u) {
  union { unsigned u; float f; } v; v.u = (unsigned)u << 16; return v.f;
}

// async global->LDS, 16B per lane (wave-uniform LDS base, per-lane global src)
__device__ __forceinline__ void gl16(const ushort* g, ushort* l) {
  __builtin_amdgcn_global_load_lds(
      (const __attribute__((address_space(1))) unsigned int*)(g),
      (__attribute__((address_space(3))) unsigned int*)(l), 16, 0, 0);
}

// ---------------------------------------------------------------------------
// prep: blocks [0,1536) convert x f32->bf16; blocks [1536,2112) transpose W.
// ---------------------------------------------------------------------------
constexpr int NCONV = 1536;

__global__ __launch_bounds__(256) void prep_k(
    const float* __restrict__ x,
    const float* __restrict__ Wq, const float* __restrict__ Wk,
    const float* __restrict__ Wv, const float* __restrict__ Wp,
    ushort* __restrict__ xb, ushort* __restrict__ Wt, ushort* __restrict__ Wpt)
{
  __shared__ float tile[64][65];
  const int bid = blockIdx.x;
  const int tid = threadIdx.x;

  if (bid < NCONV) {
    const size_t i = ((size_t)bid * 256 + tid) * 8;
    float4 a = *(const float4*)(x + i);
    float4 b = *(const float4*)(x + i + 4);
    ushort o[8] = {f2bf(a.x), f2bf(a.y), f2bf(a.z), f2bf(a.w),
                   f2bf(b.x), f2bf(b.y), f2bf(b.z), f2bf(b.w)};
    *(bf16x8*)(xb + i) = *(bf16x8*)o;
    return;
  }

  const int wb = bid - NCONV;  // 0..575
  const int tr = tid >> 4, tc = tid & 15;
  const float* src; ushort* dst;
  int k0, n0, sN, dK;
  if (wb < 432) {
    const int mat = wb / 144, rem = wb % 144;
    const int h = rem / 12, ktile = rem % 12;
    const float* W = (mat == 0) ? Wq : (mat == 1) ? Wk : Wv;
    src = W + (size_t)h * E_ * DH_;
    dst = Wt + (size_t)(mat * H_ + h) * DH_ * E_;
    k0 = ktile * 64; n0 = 0; sN = DH_; dK = E_;
  } else {
    const int rem = wb - 432;
    src = Wp;
    dst = Wpt;
    k0 = (rem / 12) * 64; n0 = (rem % 12) * 64; sN = E_; dK = E_;
  }

#pragma unroll
  for (int rr = 0; rr < 64; rr += 16) {
    float4 v = *(const float4*)(src + (size_t)(k0 + tr + rr) * sN + n0 + tc * 4);
    tile[tr + rr][tc * 4 + 0] = v.x;
    tile[tr + rr][tc * 4 + 1] = v.y;
    tile[tr + rr][tc * 4 + 2] = v.z;
    tile[tr + rr][tc * 4 + 3] = v.w;
  }
  __syncthreads();
#pragma unroll
  for (int rr = 0; rr < 64; rr += 16) {
    const int n = tr + rr;
    ushort4 o;
    o.x = f2bf(tile[tc * 4 + 0][n]);
    o.y = f2bf(tile[tc * 4 + 1][n]);
    o.z = f2bf(tile[tc * 4 + 2][n]);
    o.w = f2bf(tile[tc * 4 + 3][n]);
    *(ushort4*)(dst + (size_t)(n0 + n) * dK + k0 + tc * 4) = o;
  }
}

// ---------------------------------------------------------------------------
// QKV GEMM: 128x64 tiles (unchanged).
// ---------------------------------------------------------------------------
constexpr float QSCALE = 0.18033688f;  // 1/8 * log2(e)

__global__ __launch_bounds__(256) void qkv_fused_k(
    const ushort* __restrict__ xb, const ushort* __restrict__ Wt,
    ushort* __restrict__ q_ws, ushort* __restrict__ k_ws, ushort* __restrict__ vt_ws)
{
  __shared__ __align__(16) ushort lds[(128 + 64) * 64];  // As | Bs (24 KB)
  ushort* As = lds;
  ushort* Bs = lds + 128 * 64;

  const int seg = blockIdx.x;        // 0..35: (mat, head)
  const int m0  = blockIdx.y * 128;
  const ushort* Wh = Wt + (size_t)seg * DH_ * E_;

  const int tid  = threadIdx.x;
  const int w    = tid >> 6, l = tid & 63;
  const int lrow = l & 15, lk = l >> 4;
  const int r7   = lrow & 7;
  const int srow = l >> 3;
  const int sch  = (l & 7) ^ srow;

  f32x4 acc[2][4] = {};

  for (int k0 = 0; k0 < E_; k0 += 64) {
#pragma unroll
    for (int r = 0; r < 4; ++r) {
      const int base = r * 32 + w * 8;
      gl16(xb + (size_t)(m0 + base + srow) * E_ + k0 + sch * 8, &As[base * 64]);
      if (r < 2)
        gl16(Wh + (size_t)(base + srow) * E_ + k0 + sch * 8, &Bs[base * 64]);
    }
    __syncthreads();

#pragma unroll
    for (int kk = 0; kk < 2; ++kk) {
      const int cof = ((kk * 4 + lk) ^ r7) * 8;
      const bf16x8 a0 = *(const bf16x8*)&As[(w * 32 + lrow) * 64 + cof];
      const bf16x8 a1 = *(const bf16x8*)&As[(w * 32 + 16 + lrow) * 64 + cof];
#pragma unroll
      for (int nf = 0; nf < 4; ++nf) {
        const bf16x8 b = *(const bf16x8*)&Bs[(nf * 16 + lrow) * 64 + cof];
        acc[0][nf] = __builtin_amdgcn_mfma_f32_16x16x32_bf16(a0, b, acc[0][nf], 0, 0, 0);
        acc[1][nf] = __builtin_amdgcn_mfma_f32_16x16x32_bf16(a1, b, acc[1][nf], 0, 0, 0);
      }
    }
    __syncthreads();
  }

  const int b   = m0 >> 11;
  const int t0  = m0 & 2047;
  const int mat = seg / H_;
  const int h   = seg - mat * H_;
  const int bh  = b * H_ + h;

  if (mat != 2) {
    const float qs = (mat == 0) ? QSCALE : 1.0f;
    ushort* outw = (mat == 0) ? q_ws : k_ws;
#pragma unroll
    for (int mi = 0; mi < 2; ++mi)
#pragma unroll
      for (int i = 0; i < 4; ++i) {
        const int t = t0 + w * 32 + mi * 16 + lk * 4 + i;
        ushort* orow = outw + ((size_t)bh * T_ + t) * DH_;
#pragma unroll
        for (int nf = 0; nf < 4; ++nf)
          orow[nf * 16 + lrow] = f2bf(acc[mi][nf][i] * qs);
      }
  } else {
    ushort* Td = lds;  // [64][136]
    __syncthreads();
#pragma unroll
    for (int mi = 0; mi < 2; ++mi)
#pragma unroll
      for (int i = 0; i < 4; ++i) {
        const int tl = w * 32 + mi * 16 + lk * 4 + i;
#pragma unroll
        for (int nf = 0; nf < 4; ++nf)
          Td[(nf * 16 + lrow) * 136 + tl] = f2bf(acc[mi][nf][i]);
      }
    __syncthreads();
#pragma unroll
    for (int it = 0; it < 4; ++it) {
      const int c = tid + it * 256;
      const int d = c >> 4, sub = c & 15;
      *(bf16x8*)(vt_ws + ((size_t)bh * DH_ + d) * T_ + t0 + sub * 8) =
          *(const bf16x8*)&Td[d * 136 + sub * 8];
    }
  }
}

// ---------------------------------------------------------------------------
// Causal flash attention, split x2, IN-REGISTER P (verified in R10):
// PV computed as O^T = mfma(A=V^T frag, B=P^T frag) where B is exactly the
// S^T accumulator after exp2/cvt_pk; the MFMA k-slot permutation
// sigma(lk,j) = (j>>2)*16 + lk*4 + (j&3) is applied to the V^T A-read.
// No P LDS, no shuffles for corr/epilogue (m/l lane-uniform, q = lane&15).
// LDS 16 KB. NSPLIT=2 keeps partial traffic L2-resident (R8-verified regime).
// ---------------------------------------------------------------------------
__global__ __launch_bounds__(256, 6) void attn_split_k(
    const ushort* __restrict__ q_ws, const ushort* __restrict__ k_ws,
    const ushort* __restrict__ vt_ws, ushort* __restrict__ op_ws,
    float2* __restrict__ ml_ws)
{
  __shared__ __align__(16) ushort Ks[64 * 64];   // K tile [s][e], swizzled
  __shared__ __align__(16) ushort Vt[64 * 64];   // V^T tile [d][s], swizzled

  const int qt = 31 - (int)blockIdx.y;
  const int bh = blockIdx.x;
  const int hz = blockIdx.z;               // 0..NSPLIT-1
  const int nt = qt + 1;
  const int klo = (hz * nt) / NSPLIT;
  const int khi = ((hz + 1) * nt) / NSPLIT;
  const int q0 = qt * 64;

  const ushort* Qb  = q_ws + (size_t)bh * T_ * DH_;
  const ushort* Kb  = k_ws + (size_t)bh * T_ * DH_;
  const ushort* VTb = vt_ws + (size_t)bh * DH_ * T_;

  const int tid  = threadIdx.x;
  const int w    = tid >> 6;
  const int l    = tid & 63;
  const int lrow = l & 15;
  const int lk   = l >> 4;
  const int r7   = lrow & 7;
  const int rr   = tid >> 3;       // staging rows rr, rr+32
  const int sub  = tid & 7;
  const int swc  = sub ^ (rr & 7);

  const int st0 = rr * 64 + swc * 8;
  const int st1 = (rr + 32) * 64 + swc * 8;

  // K fragment read offsets (b128): row = ct*16+lrow, chunks lk, lk+4
  int kof0[4], kof1[4];
#pragma unroll
  for (int ct = 0; ct < 4; ++ct) {
    kof0[ct] = (ct * 16 + lrow) * 64 + ((lk ^ r7) * 8);
    kof1[ct] = (ct * 16 + lrow) * 64 + (((lk + 4) ^ r7) * 8);
  }
  // V^T A-operand b64 byte offsets (sigma permutation): col = q16*16 + lk*4
  int vof[4];
#pragma unroll
  for (int q16 = 0; q16 < 4; ++q16)
    vof[q16] = lrow * 128 + (((q16 * 2 + (lk >> 1)) ^ r7) << 4) + ((lk & 1) << 3);

  // Q fragment (B-operand of swapped QK^T): lane holds Q[q=lrow][e=lk*8+j]
  const ushort* Qrow = Qb + (size_t)(q0 + w * 16 + lrow) * DH_;
  const bf16x8 qa0 = *(const bf16x8*)(Qrow + lk * 8);
  const bf16x8 qa1 = *(const bf16x8*)(Qrow + lk * 8 + 32);
  const int qglob = q0 + w * 16 + lrow;

  float m_r = -INFINITY, l_r = 0.f;
  f32x4 oc[4] = {};   // oc[ct][i] = O^T[d = ct*16 + lk*4 + i][q = lrow]

  if (klo < khi) {
    bf16x8 kp0 = *(const bf16x8*)(Kb + (size_t)(klo * 64 + rr) * DH_ + sub * 8);
    bf16x8 kp1 = *(const bf16x8*)(Kb + (size_t)(klo * 64 + rr + 32) * DH_ + sub * 8);
    bf16x8 vp0 = *(const bf16x8*)(VTb + (size_t)rr * T_ + klo * 64 + sub * 8);
    bf16x8 vp1 = *(const bf16x8*)(VTb + (size_t)(rr + 32) * T_ + klo * 64 + sub * 8);

    for (int kt = klo; kt < khi; ++kt) {
      const int s0 = kt * 64;

      *(bf16x8*)&Ks[st0] = kp0;
      *(bf16x8*)&Ks[st1] = kp1;
      *(bf16x8*)&Vt[st0] = vp0;
      *(bf16x8*)&Vt[st1] = vp1;
      __syncthreads();

      if (kt + 1 < khi) {
        const int sn = s0 + 64;
        kp0 = *(const bf16x8*)(Kb + (size_t)(sn + rr) * DH_ + sub * 8);
        kp1 = *(const bf16x8*)(Kb + (size_t)(sn + rr + 32) * DH_ + sub * 8);
        vp0 = *(const bf16x8*)(VTb + (size_t)rr * T_ + sn + sub * 8);
        vp1 = *(const bf16x8*)(VTb + (size_t)(rr + 32) * T_ + sn + sub * 8);
      }

      // S^T = K Q^T : st[ct][i] -> s = s0+ct*16+lk*4+i, q = lrow
      f32x4 st[4];
#pragma unroll
      for (int ct = 0; ct < 4; ++ct) {
        const bf16x8 kb0 = *(const bf16x8*)&Ks[kof0[ct]];
        const bf16x8 kb1 = *(const bf16x8*)&Ks[kof1[ct]];
        f32x4 z = {0.f, 0.f, 0.f, 0.f};
        z = __builtin_amdgcn_mfma_f32_16x16x32_bf16(kb0, qa0, z, 0, 0, 0);
        st[ct] = __builtin_amdgcn_mfma_f32_16x16x32_bf16(kb1, qa1, z, 0, 0, 0);
      }

      if (kt == qt) {  // diagonal tile only
#pragma unroll
        for (int ct = 0; ct < 4; ++ct)
#pragma unroll
          for (int i = 0; i < 4; ++i)
            if (s0 + ct * 16 + lk * 4 + i > qglob) st[ct][i] = -INFINITY;
      }

      float mc[4];
#pragma unroll
      for (int ct = 0; ct < 4; ++ct)
        mc[ct] = fmaxf(fmaxf(st[ct][0], st[ct][1]), fmaxf(st[ct][2], st[ct][3]));
      float mx = fmaxf(fmaxf(mc[0], mc[1]), fmaxf(mc[2], mc[3]));
      mx = fmaxf(mx, __shfl_xor(mx, 16));
      mx = fmaxf(mx, __shfl_xor(mx, 32));

      // defer-max; corr lane-uniform (q = lrow) -> no shuffles
      if (__any(mx > m_r + 8.f)) {
        const float mn   = fmaxf(m_r, mx);
        const float corr = exp2f(m_r - mn);
        m_r = mn;
        l_r *= corr;
#pragma unroll
        for (int ct = 0; ct < 4; ++ct)
#pragma unroll
          for (int i = 0; i < 4; ++i) oc[ct][i] *= corr;
      }

      float sc[4];
#pragma unroll
      for (int ct = 0; ct < 4; ++ct) {
#pragma unroll
        for (int i = 0; i < 4; ++i) st[ct][i] = exp2f(st[ct][i] - m_r);
        sc[ct] = (st[ct][0] + st[ct][1]) + (st[ct][2] + st[ct][3]);
      }
      float rs = (sc[0] + sc[1]) + (sc[2] + sc[3]);
      rs += __shfl_xor(rs, 16);
      rs += __shfl_xor(rs, 32);
      l_r += rs;

      // P^T fragments IN REGISTERS (B-operand slots match S^T layout)
      Frag pb0, pb1;
      asm("v_cvt_pk_bf16_f32 %0, %1, %2" : "=v"(pb0.w[0]) : "v"(st[0][0]), "v"(st[0][1]));
      asm("v_cvt_pk_bf16_f32 %0, %1, %2" : "=v"(pb0.w[1]) : "v"(st[0][2]), "v"(st[0][3]));
      asm("v_cvt_pk_bf16_f32 %0, %1, %2" : "=v"(pb0.w[2]) : "v"(st[1][0]), "v"(st[1][1]));
      asm("v_cvt_pk_bf16_f32 %0, %1, %2" : "=v"(pb0.w[3]) : "v"(st[1][2]), "v"(st[1][3]));
      asm("v_cvt_pk_bf16_f32 %0, %1, %2" : "=v"(pb1.w[0]) : "v"(st[2][0]), "v"(st[2][1]));
      asm("v_cvt_pk_bf16_f32 %0, %1, %2" : "=v"(pb1.w[1]) : "v"(st[2][2]), "v"(st[2][3]));
      asm("v_cvt_pk_bf16_f32 %0, %1, %2" : "=v"(pb1.w[2]) : "v"(st[3][0]), "v"(st[3][1]));
      asm("v_cvt_pk_bf16_f32 %0, %1, %2" : "=v"(pb1.w[3]) : "v"(st[3][2]), "v"(st[3][3]));

      // O^T += V^T . P^T  (A-read applies sigma: cols q16*16 + lk*4)
#pragma unroll
      for (int ct = 0; ct < 4; ++ct) {
        const char* vb = (const char*)Vt + ct * 2048;
        Frag va0, va1;
        va0.u[0] = *(const uint2*)(vb + vof[0]);
        va0.u[1] = *(const uint2*)(vb + vof[1]);
        va1.u[0] = *(const uint2*)(vb + vof[2]);
        va1.u[1] = *(const uint2*)(vb + vof[3]);
        oc[ct] = __builtin_amdgcn_mfma_f32_16x16x32_bf16(va0.v, pb0.v, oc[ct], 0, 0, 0);
        oc[ct] = __builtin_amdgcn_mfma_f32_16x16x32_bf16(va1.v, pb1.v, oc[ct], 0, 0, 0);
      }
      __syncthreads();
    }
  }

  // epilogue: unnormalized O^T partial + per-row (m,l); lane-uniform in q
  const size_t pb = (size_t)(hz * BH_ + bh) * T_;
  const int t = q0 + w * 16 + lrow;
  if (lk == 0)
    ml_ws[pb + t] = make_float2(m_r, l_r);
  ushort* orow = op_ws + (pb + t) * DH_;
#pragma unroll
  for (int ct = 0; ct < 4; ++ct) {
    ushort4 o4;
    o4.x = f2bf(oc[ct][0]); o4.y = f2bf(oc[ct][1]);
    o4.z = f2bf(oc[ct][2]); o4.w = f2bf(oc[ct][3]);
    *(ushort4*)(orow + ct * 16 + lk * 4) = o4;
  }
}

// ---------------------------------------------------------------------------
// Out-proj GEMM with fused split-k combine (64x64 tiles).
// ---------------------------------------------------------------------------
__global__ __launch_bounds__(256) void proj_fused_k(
    const ushort* __restrict__ op_ws, const float2* __restrict__ ml_ws,
    const ushort* __restrict__ Wpt, const float* __restrict__ bp,
    float* __restrict__ out)
{
  __shared__ __align__(16) ushort lds[(64 + 64) * 64];  // As | Bs (16 KB)
  ushort* As = lds;
  ushort* Bs = lds + 64 * 64;

  const int n0 = blockIdx.x * 64;
  const int m0 = blockIdx.y * 64;
  const int b  = m0 >> 11;
  const int t0 = m0 & 2047;

  const int tid  = threadIdx.x;
  const int w    = tid >> 6, l = tid & 63;
  const int lrow = l & 15, lk = l >> 4;
  const int r7   = lrow & 7;
  const int srow = l >> 3;
  const int sch  = (l & 7) ^ srow;
  const int ar = tid >> 2;          // A-staging row 0..63
  const int cc = tid & 3;           // 16-elem chunk
  const int a7 = ar & 7;

  f32x4 acc[4] = {};

  for (int k0 = 0; k0 < E_; k0 += 64) {
    const int h  = k0 >> 6;
    const int bh = b * H_ + h;

#pragma unroll
    for (int r = 0; r < 2; ++r) {
      const int base = r * 32 + w * 8;
      gl16(Wpt + (size_t)(n0 + base + srow) * E_ + k0 + sch * 8, &Bs[base * 64]);
    }

    // A staging: combine NSPLIT partials in regs, swizzled ds_write
    {
      const int t = t0 + ar;
      size_t ix[NSPLIT];
      float2 ml[NSPLIT];
#pragma unroll
      for (int z = 0; z < NSPLIT; ++z) {
        ix[z] = ((size_t)(z * BH_ + bh) * T_ + t);
        ml[z] = ml_ws[ix[z]];
      }
      float m = ml[0].x;
#pragma unroll
      for (int z = 1; z < NSPLIT; ++z) m = fmaxf(m, ml[z].x);
      float f[NSPLIT];
      float den = 0.f;
#pragma unroll
      for (int z = 0; z < NSPLIT; ++z) {
        f[z] = exp2f(ml[z].x - m);
        den += f[z] * ml[z].y;
      }
      const float inv = 1.0f / den;
#pragma unroll
      for (int z = 0; z < NSPLIT; ++z) f[z] *= inv;

      float o[16] = {};
#pragma unroll
      for (int z = 0; z < NSPLIT; ++z) {
        const ushort* p = op_ws + ix[z] * DH_ + cc * 16;
        bf16x8 x0 = *(const bf16x8*)p;
        bf16x8 x1 = *(const bf16x8*)(p + 8);
#pragma unroll
        for (int j = 0; j < 8; ++j) {
          o[j]     += f[z] * bf2f((ushort)x0[j]);
          o[8 + j] += f[z] * bf2f((ushort)x1[j]);
        }
      }
      ushort ob[16];
#pragma unroll
      for (int j = 0; j < 16; ++j) ob[j] = f2bf(o[j]);
      *(bf16x8*)&As[ar * 64 + ((2 * cc) ^ a7) * 8]     = *(const bf16x8*)&ob[0];
      *(bf16x8*)&As[ar * 64 + ((2 * cc + 1) ^ a7) * 8] = *(const bf16x8*)&ob[8];
    }
    __syncthreads();

#pragma unroll
    for (int kk = 0; kk < 2; ++kk) {
      const int cof = ((kk * 4 + lk) ^ r7) * 8;
      const bf16x8 a = *(const bf16x8*)&As[(w * 16 + lrow) * 64 + cof];
#pragma unroll
      for (int nf = 0; nf < 4; ++nf) {
        const bf16x8 bb = *(const bf16x8*)&Bs[(nf * 16 + lrow) * 64 + cof];
        acc[nf] = __builtin_amdgcn_mfma_f32_16x16x32_bf16(a, bb, acc[nf], 0, 0, 0);
      }
    }
    __syncthreads();
  }

  float bias[4];
#pragma unroll
  for (int nf = 0; nf < 4; ++nf) bias[nf] = bp[n0 + nf * 16 + lrow];

#pragma unroll
  for (int i = 0; i < 4; ++i) {
    const int m = m0 + w * 16 + lk * 4 + i;
    float* orow = out + (size_t)m * E_ + n0;
#pragma unroll
    for (int nf = 0; nf < 4; ++nf)
      orow[nf * 16 + lrow] = acc[nf][i] + bias[nf];
  }
}

}  // namespace

extern "C" void kernel_launch(void* const* d_in, const int* in_sizes, int n_in,
                              void* d_out, int out_size, void* d_ws, size_t ws_size,
                              hipStream_t stream) {
  const float* x  = (const float*)d_in[0];
  const float* Wq = (const float*)d_in[1];
  const float* Wk = (const float*)d_in[2];
  const float* Wv = (const float*)d_in[3];
  const float* Wp = (const float*)d_in[4];
  const float* bp = (const float*)d_in[5];
  float* out = (float*)d_out;

  const size_t nx  = (size_t)M_ * E_;            // 3,145,728
  const size_t nwt = (size_t)3 * H_ * DH_ * E_;  // 1,769,472
  const size_t nwp = (size_t)E_ * E_;            // 589,824
  const size_t per = (size_t)BH_ * T_ * DH_;     // 3,145,728

  ushort* xb    = (ushort*)d_ws;
  ushort* Wt    = xb + nx;
  ushort* Wpt   = Wt + nwt;
  ushort* q_ws  = Wpt + nwp;
  ushort* k_ws  = q_ws + per;
  ushort* vt_ws = k_ws + per;     // [bh][d][t]
  ushort* op_ws = vt_ws + per;    // [NSPLIT][bh][t][64] partials
  float2* ml_ws = (float2*)(op_ws + NSPLIT * per);  // [NSPLIT][bh][t]

  prep_k<<<dim3(NCONV + 576), 256, 0, stream>>>(x, Wq, Wk, Wv, Wp, xb, Wt, Wpt);
  qkv_fused_k<<<dim3(36, 32), 256, 0, stream>>>(xb, Wt, q_ws, k_ws, vt_ws);
  attn_split_k<<<dim3(24, 32, NSPLIT), 256, 0, stream>>>(q_ws, k_ws, vt_ws, op_ws, ml_ws);
  proj_fused_k<<<dim3(12, 64), 256, 0, stream>>>(op_ws, ml_ws, Wpt, bp, out);
}

// Round 12
// 127.542 us; speedup vs baseline: 1.1373x; 1.0581x over previous
//
#include <hip/hip_runtime.h>
#include <math.h>

namespace {

constexpr int E_  = 768;
constexpr int H_  = 12;
constexpr int DH_ = 64;
constexpr int T_  = 2048;
constexpr int B_  = 2;
constexpr int M_  = B_ * T_;  // 4096
constexpr int BH_ = B_ * H_;  // 24
constexpr int NSPLIT = 2;     // attention k-range split factor

typedef __attribute__((ext_vector_type(8))) short bf16x8;
typedef __attribute__((ext_vector_type(4))) float f32x4;

union Frag { bf16x8 v; uint2 u[2]; unsigned w[4]; };

__device__ inline ushort f2bf(float f) {
  union { float f; unsigned u; } v; v.f = f;
  unsigned u = v.u + 0x7FFFu + ((v.u >> 16) & 1u);  // RNE
  return (ushort)(u >> 16);
}
__device__ inline float bf2f(ushort u) {
  union { unsigned u; float f; } v; v.u = (unsigned)u << 16; return v.f;
}

// async global->LDS, 16B per lane (wave-uniform LDS base, per-lane global src)
__device__ __forceinline__ void gl16(const ushort* g, ushort* l) {
  __builtin_amdgcn_global_load_lds(
      (const __attribute__((address_space(1))) unsigned int*)(g),
      (__attribute__((address_space(3))) unsigned int*)(l), 16, 0, 0);
}

// ---------------------------------------------------------------------------
// prep: blocks [0,1536) convert x f32->bf16; blocks [1536,2112) transpose W.
// ---------------------------------------------------------------------------
constexpr int NCONV = 1536;

__global__ __launch_bounds__(256) void prep_k(
    const float* __restrict__ x,
    const float* __restrict__ Wq, const float* __restrict__ Wk,
    const float* __restrict__ Wv, const float* __restrict__ Wp,
    ushort* __restrict__ xb, ushort* __restrict__ Wt, ushort* __restrict__ Wpt)
{
  __shared__ float tile[64][65];
  const int bid = blockIdx.x;
  const int tid = threadIdx.x;

  if (bid < NCONV) {
    const size_t i = ((size_t)bid * 256 + tid) * 8;
    float4 a = *(const float4*)(x + i);
    float4 b = *(const float4*)(x + i + 4);
    ushort o[8] = {f2bf(a.x), f2bf(a.y), f2bf(a.z), f2bf(a.w),
                   f2bf(b.x), f2bf(b.y), f2bf(b.z), f2bf(b.w)};
    *(bf16x8*)(xb + i) = *(bf16x8*)o;
    return;
  }

  const int wb = bid - NCONV;  // 0..575
  const int tr = tid >> 4, tc = tid & 15;
  const float* src; ushort* dst;
  int k0, n0, sN, dK;
  if (wb < 432) {
    const int mat = wb / 144, rem = wb % 144;
    const int h = rem / 12, ktile = rem % 12;
    const float* W = (mat == 0) ? Wq : (mat == 1) ? Wk : Wv;
    src = W + (size_t)h * E_ * DH_;
    dst = Wt + (size_t)(mat * H_ + h) * DH_ * E_;
    k0 = ktile * 64; n0 = 0; sN = DH_; dK = E_;
  } else {
    const int rem = wb - 432;
    src = Wp;
    dst = Wpt;
    k0 = (rem / 12) * 64; n0 = (rem % 12) * 64; sN = E_; dK = E_;
  }

#pragma unroll
  for (int rr = 0; rr < 64; rr += 16) {
    float4 v = *(const float4*)(src + (size_t)(k0 + tr + rr) * sN + n0 + tc * 4);
    tile[tr + rr][tc * 4 + 0] = v.x;
    tile[tr + rr][tc * 4 + 1] = v.y;
    tile[tr + rr][tc * 4 + 2] = v.z;
    tile[tr + rr][tc * 4 + 3] = v.w;
  }
  __syncthreads();
#pragma unroll
  for (int rr = 0; rr < 64; rr += 16) {
    const int n = tr + rr;
    ushort4 o;
    o.x = f2bf(tile[tc * 4 + 0][n]);
    o.y = f2bf(tile[tc * 4 + 1][n]);
    o.z = f2bf(tile[tc * 4 + 2][n]);
    o.w = f2bf(tile[tc * 4 + 3][n]);
    *(ushort4*)(dst + (size_t)(n0 + n) * dK + k0 + tc * 4) = o;
  }
}

// ---------------------------------------------------------------------------
// QKV GEMM: 128x64 tiles (unchanged).
// ---------------------------------------------------------------------------
constexpr float QSCALE = 0.18033688f;  // 1/8 * log2(e)

__global__ __launch_bounds__(256) void qkv_fused_k(
    const ushort* __restrict__ xb, const ushort* __restrict__ Wt,
    ushort* __restrict__ q_ws, ushort* __restrict__ k_ws, ushort* __restrict__ vt_ws)
{
  __shared__ __align__(16) ushort lds[(128 + 64) * 64];  // As | Bs (24 KB)
  ushort* As = lds;
  ushort* Bs = lds + 128 * 64;

  const int seg = blockIdx.x;        // 0..35: (mat, head)
  const int m0  = blockIdx.y * 128;
  const ushort* Wh = Wt + (size_t)seg * DH_ * E_;

  const int tid  = threadIdx.x;
  const int w    = tid >> 6, l = tid & 63;
  const int lrow = l & 15, lk = l >> 4;
  const int r7   = lrow & 7;
  const int srow = l >> 3;
  const int sch  = (l & 7) ^ srow;

  f32x4 acc[2][4] = {};

  for (int k0 = 0; k0 < E_; k0 += 64) {
#pragma unroll
    for (int r = 0; r < 4; ++r) {
      const int base = r * 32 + w * 8;
      gl16(xb + (size_t)(m0 + base + srow) * E_ + k0 + sch * 8, &As[base * 64]);
      if (r < 2)
        gl16(Wh + (size_t)(base + srow) * E_ + k0 + sch * 8, &Bs[base * 64]);
    }
    __syncthreads();

#pragma unroll
    for (int kk = 0; kk < 2; ++kk) {
      const int cof = ((kk * 4 + lk) ^ r7) * 8;
      const bf16x8 a0 = *(const bf16x8*)&As[(w * 32 + lrow) * 64 + cof];
      const bf16x8 a1 = *(const bf16x8*)&As[(w * 32 + 16 + lrow) * 64 + cof];
#pragma unroll
      for (int nf = 0; nf < 4; ++nf) {
        const bf16x8 b = *(const bf16x8*)&Bs[(nf * 16 + lrow) * 64 + cof];
        acc[0][nf] = __builtin_amdgcn_mfma_f32_16x16x32_bf16(a0, b, acc[0][nf], 0, 0, 0);
        acc[1][nf] = __builtin_amdgcn_mfma_f32_16x16x32_bf16(a1, b, acc[1][nf], 0, 0, 0);
      }
    }
    __syncthreads();
  }

  const int b   = m0 >> 11;
  const int t0  = m0 & 2047;
  const int mat = seg / H_;
  const int h   = seg - mat * H_;
  const int bh  = b * H_ + h;

  if (mat != 2) {
    const float qs = (mat == 0) ? QSCALE : 1.0f;
    ushort* outw = (mat == 0) ? q_ws : k_ws;
#pragma unroll
    for (int mi = 0; mi < 2; ++mi)
#pragma unroll
      for (int i = 0; i < 4; ++i) {
        const int t = t0 + w * 32 + mi * 16 + lk * 4 + i;
        ushort* orow = outw + ((size_t)bh * T_ + t) * DH_;
#pragma unroll
        for (int nf = 0; nf < 4; ++nf)
          orow[nf * 16 + lrow] = f2bf(acc[mi][nf][i] * qs);
      }
  } else {
    ushort* Td = lds;  // [64][136]
    __syncthreads();
#pragma unroll
    for (int mi = 0; mi < 2; ++mi)
#pragma unroll
      for (int i = 0; i < 4; ++i) {
        const int tl = w * 32 + mi * 16 + lk * 4 + i;
#pragma unroll
        for (int nf = 0; nf < 4; ++nf)
          Td[(nf * 16 + lrow) * 136 + tl] = f2bf(acc[mi][nf][i]);
      }
    __syncthreads();
#pragma unroll
    for (int it = 0; it < 4; ++it) {
      const int c = tid + it * 256;
      const int d = c >> 4, sub = c & 15;
      *(bf16x8*)(vt_ws + ((size_t)bh * DH_ + d) * T_ + t0 + sub * 8) =
          *(const bf16x8*)&Td[d * 136 + sub * 8];
    }
  }
}

// ---------------------------------------------------------------------------
// Causal flash attention, split x2, in-register P (R10-verified math).
// FIX vs R10/R11: epilogue transposes O^T -> O through per-wave LDS so the
// global partial-O stores are contiguous 1KB spans (two b128 per wave) --
// removes the ~10x HBM write amplification the scattered 8B stores caused.
// ---------------------------------------------------------------------------
__global__ __launch_bounds__(256, 6) void attn_split_k(
    const ushort* __restrict__ q_ws, const ushort* __restrict__ k_ws,
    const ushort* __restrict__ vt_ws, ushort* __restrict__ op_ws,
    float2* __restrict__ ml_ws)
{
  __shared__ __align__(16) ushort Ks[64 * 64];   // K tile [s][e], swizzled
  __shared__ __align__(16) ushort Vt[64 * 64];   // V^T tile [d][s], swizzled
  __shared__ __align__(16) ushort Ot[4][16 * 72];  // per-wave O transpose buf

  const int qt = 31 - (int)blockIdx.y;
  const int bh = blockIdx.x;
  const int hz = blockIdx.z;               // 0..NSPLIT-1
  const int nt = qt + 1;
  const int klo = (hz * nt) / NSPLIT;
  const int khi = ((hz + 1) * nt) / NSPLIT;
  const int q0 = qt * 64;

  const ushort* Qb  = q_ws + (size_t)bh * T_ * DH_;
  const ushort* Kb  = k_ws + (size_t)bh * T_ * DH_;
  const ushort* VTb = vt_ws + (size_t)bh * DH_ * T_;

  const int tid  = threadIdx.x;
  const int w    = tid >> 6;
  const int l    = tid & 63;
  const int lrow = l & 15;
  const int lk   = l >> 4;
  const int r7   = lrow & 7;
  const int rr   = tid >> 3;       // staging rows rr, rr+32
  const int sub  = tid & 7;
  const int swc  = sub ^ (rr & 7);

  const int st0 = rr * 64 + swc * 8;
  const int st1 = (rr + 32) * 64 + swc * 8;

  // K fragment read offsets (b128): row = ct*16+lrow, chunks lk, lk+4
  int kof0[4], kof1[4];
#pragma unroll
  for (int ct = 0; ct < 4; ++ct) {
    kof0[ct] = (ct * 16 + lrow) * 64 + ((lk ^ r7) * 8);
    kof1[ct] = (ct * 16 + lrow) * 64 + (((lk + 4) ^ r7) * 8);
  }
  // V^T A-operand b64 byte offsets (sigma permutation): col = q16*16 + lk*4
  int vof[4];
#pragma unroll
  for (int q16 = 0; q16 < 4; ++q16)
    vof[q16] = lrow * 128 + (((q16 * 2 + (lk >> 1)) ^ r7) << 4) + ((lk & 1) << 3);

  // Q fragment (B-operand of swapped QK^T): lane holds Q[q=lrow][e=lk*8+j]
  const ushort* Qrow = Qb + (size_t)(q0 + w * 16 + lrow) * DH_;
  const bf16x8 qa0 = *(const bf16x8*)(Qrow + lk * 8);
  const bf16x8 qa1 = *(const bf16x8*)(Qrow + lk * 8 + 32);
  const int qglob = q0 + w * 16 + lrow;

  float m_r = -INFINITY, l_r = 0.f;
  f32x4 oc[4] = {};   // oc[ct][i] = O^T[d = ct*16 + lk*4 + i][q = lrow]

  if (klo < khi) {
    bf16x8 kp0 = *(const bf16x8*)(Kb + (size_t)(klo * 64 + rr) * DH_ + sub * 8);
    bf16x8 kp1 = *(const bf16x8*)(Kb + (size_t)(klo * 64 + rr + 32) * DH_ + sub * 8);
    bf16x8 vp0 = *(const bf16x8*)(VTb + (size_t)rr * T_ + klo * 64 + sub * 8);
    bf16x8 vp1 = *(const bf16x8*)(VTb + (size_t)(rr + 32) * T_ + klo * 64 + sub * 8);

    for (int kt = klo; kt < khi; ++kt) {
      const int s0 = kt * 64;

      *(bf16x8*)&Ks[st0] = kp0;
      *(bf16x8*)&Ks[st1] = kp1;
      *(bf16x8*)&Vt[st0] = vp0;
      *(bf16x8*)&Vt[st1] = vp1;
      __syncthreads();

      if (kt + 1 < khi) {
        const int sn = s0 + 64;
        kp0 = *(const bf16x8*)(Kb + (size_t)(sn + rr) * DH_ + sub * 8);
        kp1 = *(const bf16x8*)(Kb + (size_t)(sn + rr + 32) * DH_ + sub * 8);
        vp0 = *(const bf16x8*)(VTb + (size_t)rr * T_ + sn + sub * 8);
        vp1 = *(const bf16x8*)(VTb + (size_t)(rr + 32) * T_ + sn + sub * 8);
      }

      // S^T = K Q^T : st[ct][i] -> s = s0+ct*16+lk*4+i, q = lrow
      f32x4 st[4];
#pragma unroll
      for (int ct = 0; ct < 4; ++ct) {
        const bf16x8 kb0 = *(const bf16x8*)&Ks[kof0[ct]];
        const bf16x8 kb1 = *(const bf16x8*)&Ks[kof1[ct]];
        f32x4 z = {0.f, 0.f, 0.f, 0.f};
        z = __builtin_amdgcn_mfma_f32_16x16x32_bf16(kb0, qa0, z, 0, 0, 0);
        st[ct] = __builtin_amdgcn_mfma_f32_16x16x32_bf16(kb1, qa1, z, 0, 0, 0);
      }

      if (kt == qt) {  // diagonal tile only
#pragma unroll
        for (int ct = 0; ct < 4; ++ct)
#pragma unroll
          for (int i = 0; i < 4; ++i)
            if (s0 + ct * 16 + lk * 4 + i > qglob) st[ct][i] = -INFINITY;
      }

      float mc[4];
#pragma unroll
      for (int ct = 0; ct < 4; ++ct)
        mc[ct] = fmaxf(fmaxf(st[ct][0], st[ct][1]), fmaxf(st[ct][2], st[ct][3]));
      float mx = fmaxf(fmaxf(mc[0], mc[1]), fmaxf(mc[2], mc[3]));
      mx = fmaxf(mx, __shfl_xor(mx, 16));
      mx = fmaxf(mx, __shfl_xor(mx, 32));

      // defer-max; corr lane-uniform (q = lrow) -> no shuffles
      if (__any(mx > m_r + 8.f)) {
        const float mn   = fmaxf(m_r, mx);
        const float corr = exp2f(m_r - mn);
        m_r = mn;
        l_r *= corr;
#pragma unroll
        for (int ct = 0; ct < 4; ++ct)
#pragma unroll
          for (int i = 0; i < 4; ++i) oc[ct][i] *= corr;
      }

      float sc[4];
#pragma unroll
      for (int ct = 0; ct < 4; ++ct) {
#pragma unroll
        for (int i = 0; i < 4; ++i) st[ct][i] = exp2f(st[ct][i] - m_r);
        sc[ct] = (st[ct][0] + st[ct][1]) + (st[ct][2] + st[ct][3]);
      }
      float rs = (sc[0] + sc[1]) + (sc[2] + sc[3]);
      rs += __shfl_xor(rs, 16);
      rs += __shfl_xor(rs, 32);
      l_r += rs;

      // P^T fragments IN REGISTERS (B-operand slots match S^T layout)
      Frag pb0, pb1;
      asm("v_cvt_pk_bf16_f32 %0, %1, %2" : "=v"(pb0.w[0]) : "v"(st[0][0]), "v"(st[0][1]));
      asm("v_cvt_pk_bf16_f32 %0, %1, %2" : "=v"(pb0.w[1]) : "v"(st[0][2]), "v"(st[0][3]));
      asm("v_cvt_pk_bf16_f32 %0, %1, %2" : "=v"(pb0.w[2]) : "v"(st[1][0]), "v"(st[1][1]));
      asm("v_cvt_pk_bf16_f32 %0, %1, %2" : "=v"(pb0.w[3]) : "v"(st[1][2]), "v"(st[1][3]));
      asm("v_cvt_pk_bf16_f32 %0, %1, %2" : "=v"(pb1.w[0]) : "v"(st[2][0]), "v"(st[2][1]));
      asm("v_cvt_pk_bf16_f32 %0, %1, %2" : "=v"(pb1.w[1]) : "v"(st[2][2]), "v"(st[2][3]));
      asm("v_cvt_pk_bf16_f32 %0, %1, %2" : "=v"(pb1.w[2]) : "v"(st[3][0]), "v"(st[3][1]));
      asm("v_cvt_pk_bf16_f32 %0, %1, %2" : "=v"(pb1.w[3]) : "v"(st[3][2]), "v"(st[3][3]));

      // O^T += V^T . P^T  (A-read applies sigma: cols q16*16 + lk*4)
#pragma unroll
      for (int ct = 0; ct < 4; ++ct) {
        const char* vb = (const char*)Vt + ct * 2048;
        Frag va0, va1;
        va0.u[0] = *(const uint2*)(vb + vof[0]);
        va0.u[1] = *(const uint2*)(vb + vof[1]);
        va1.u[0] = *(const uint2*)(vb + vof[2]);
        va1.u[1] = *(const uint2*)(vb + vof[3]);
        oc[ct] = __builtin_amdgcn_mfma_f32_16x16x32_bf16(va0.v, pb0.v, oc[ct], 0, 0, 0);
        oc[ct] = __builtin_amdgcn_mfma_f32_16x16x32_bf16(va1.v, pb1.v, oc[ct], 0, 0, 0);
      }
      __syncthreads();
    }
  }

  // ---- epilogue: transpose O^T -> O via per-wave LDS; contiguous stores ----
  const size_t pb = (size_t)(hz * BH_ + bh) * T_;
  const int t_base = q0 + w * 16;
  if (lk == 0)
    ml_ws[pb + t_base + lrow] = make_float2(m_r, l_r);

  ushort* Tw = &Ot[w][0];  // [16][72], wave-private
#pragma unroll
  for (int ct = 0; ct < 4; ++ct) {
    unsigned lo, hi;
    asm("v_cvt_pk_bf16_f32 %0, %1, %2" : "=v"(lo) : "v"(oc[ct][0]), "v"(oc[ct][1]));
    asm("v_cvt_pk_bf16_f32 %0, %1, %2" : "=v"(hi) : "v"(oc[ct][2]), "v"(oc[ct][3]));
    uint2 pk; pk.x = lo; pk.y = hi;
    *(uint2*)&Tw[lrow * 72 + ct * 16 + lk * 4] = pk;  // row q=lrow, cols d..d+3
  }
  // wave-local write->read; compiler inserts lgkmcnt
  const int er = l >> 3;   // 0..7
  const int ec = l & 7;    // 16B chunk
#pragma unroll
  for (int half = 0; half < 2; ++half) {
    const int r = er + half * 8;
    const bf16x8 v = *(const bf16x8*)&Tw[r * 72 + ec * 8];
    *(bf16x8*)(op_ws + (pb + t_base + r) * DH_ + ec * 8) = v;  // 1KB span/wave
  }
}

// ---------------------------------------------------------------------------
// Out-proj GEMM with fused split-k combine (64x64 tiles).
// ---------------------------------------------------------------------------
__global__ __launch_bounds__(256) void proj_fused_k(
    const ushort* __restrict__ op_ws, const float2* __restrict__ ml_ws,
    const ushort* __restrict__ Wpt, const float* __restrict__ bp,
    float* __restrict__ out)
{
  __shared__ __align__(16) ushort lds[(64 + 64) * 64];  // As | Bs (16 KB)
  ushort* As = lds;
  ushort* Bs = lds + 64 * 64;

  const int n0 = blockIdx.x * 64;
  const int m0 = blockIdx.y * 64;
  const int b  = m0 >> 11;
  const int t0 = m0 & 2047;

  const int tid  = threadIdx.x;
  const int w    = tid >> 6, l = tid & 63;
  const int lrow = l & 15, lk = l >> 4;
  const int r7   = lrow & 7;
  const int srow = l >> 3;
  const int sch  = (l & 7) ^ srow;
  const int ar = tid >> 2;          // A-staging row 0..63
  const int cc = tid & 3;           // 16-elem chunk
  const int a7 = ar & 7;

  f32x4 acc[4] = {};

  for (int k0 = 0; k0 < E_; k0 += 64) {
    const int h  = k0 >> 6;
    const int bh = b * H_ + h;

#pragma unroll
    for (int r = 0; r < 2; ++r) {
      const int base = r * 32 + w * 8;
      gl16(Wpt + (size_t)(n0 + base + srow) * E_ + k0 + sch * 8, &Bs[base * 64]);
    }

    // A staging: combine NSPLIT partials in regs, swizzled ds_write
    {
      const int t = t0 + ar;
      size_t ix[NSPLIT];
      float2 ml[NSPLIT];
#pragma unroll
      for (int z = 0; z < NSPLIT; ++z) {
        ix[z] = ((size_t)(z * BH_ + bh) * T_ + t);
        ml[z] = ml_ws[ix[z]];
      }
      float m = ml[0].x;
#pragma unroll
      for (int z = 1; z < NSPLIT; ++z) m = fmaxf(m, ml[z].x);
      float f[NSPLIT];
      float den = 0.f;
#pragma unroll
      for (int z = 0; z < NSPLIT; ++z) {
        f[z] = exp2f(ml[z].x - m);
        den += f[z] * ml[z].y;
      }
      const float inv = 1.0f / den;
#pragma unroll
      for (int z = 0; z < NSPLIT; ++z) f[z] *= inv;

      float o[16] = {};
#pragma unroll
      for (int z = 0; z < NSPLIT; ++z) {
        const ushort* p = op_ws + ix[z] * DH_ + cc * 16;
        bf16x8 x0 = *(const bf16x8*)p;
        bf16x8 x1 = *(const bf16x8*)(p + 8);
#pragma unroll
        for (int j = 0; j < 8; ++j) {
          o[j]     += f[z] * bf2f((ushort)x0[j]);
          o[8 + j] += f[z] * bf2f((ushort)x1[j]);
        }
      }
      ushort ob[16];
#pragma unroll
      for (int j = 0; j < 16; ++j) ob[j] = f2bf(o[j]);
      *(bf16x8*)&As[ar * 64 + ((2 * cc) ^ a7) * 8]     = *(const bf16x8*)&ob[0];
      *(bf16x8*)&As[ar * 64 + ((2 * cc + 1) ^ a7) * 8] = *(const bf16x8*)&ob[8];
    }
    __syncthreads();

#pragma unroll
    for (int kk = 0; kk < 2; ++kk) {
      const int cof = ((kk * 4 + lk) ^ r7) * 8;
      const bf16x8 a = *(const bf16x8*)&As[(w * 16 + lrow) * 64 + cof];
#pragma unroll
      for (int nf = 0; nf < 4; ++nf) {
        const bf16x8 bb = *(const bf16x8*)&Bs[(nf * 16 + lrow) * 64 + cof];
        acc[nf] = __builtin_amdgcn_mfma_f32_16x16x32_bf16(a, bb, acc[nf], 0, 0, 0);
      }
    }
    __syncthreads();
  }

  float bias[4];
#pragma unroll
  for (int nf = 0; nf < 4; ++nf) bias[nf] = bp[n0 + nf * 16 + lrow];

#pragma unroll
  for (int i = 0; i < 4; ++i) {
    const int m = m0 + w * 16 + lk * 4 + i;
    float* orow = out + (size_t)m * E_ + n0;
#pragma unroll
    for (int nf = 0; nf < 4; ++nf)
      orow[nf * 16 + lrow] = acc[nf][i] + bias[nf];
  }
}

}  // namespace

extern "C" void kernel_launch(void* const* d_in, const int* in_sizes, int n_in,
                              void* d_out, int out_size, void* d_ws, size_t ws_size,
                              hipStream_t stream) {
  const float* x  = (const float*)d_in[0];
  const float* Wq = (const float*)d_in[1];
  const float* Wk = (const float*)d_in[2];
  const float* Wv = (const float*)d_in[3];
  const float* Wp = (const float*)d_in[4];
  const float* bp = (const float*)d_in[5];
  float* out = (float*)d_out;

  const size_t nx  = (size_t)M_ * E_;            // 3,145,728
  const size_t nwt = (size_t)3 * H_ * DH_ * E_;  // 1,769,472
  const size_t nwp = (size_t)E_ * E_;            // 589,824
  const size_t per = (size_t)BH_ * T_ * DH_;     // 3,145,728

  ushort* xb    = (ushort*)d_ws;
  ushort* Wt    = xb + nx;
  ushort* Wpt   = Wt + nwt;
  ushort* q_ws  = Wpt + nwp;
  ushort* k_ws  = q_ws + per;
  ushort* vt_ws = k_ws + per;     // [bh][d][t]
  ushort* op_ws = vt_ws + per;    // [NSPLIT][bh][t][64] partials
  float2* ml_ws = (float2*)(op_ws + NSPLIT * per);  // [NSPLIT][bh][t]

  prep_k<<<dim3(NCONV + 576), 256, 0, stream>>>(x, Wq, Wk, Wv, Wp, xb, Wt, Wpt);
  qkv_fused_k<<<dim3(36, 32), 256, 0, stream>>>(xb, Wt, q_ws, k_ws, vt_ws);
  attn_split_k<<<dim3(24, 32, NSPLIT), 256, 0, stream>>>(q_ws, k_ws, vt_ws, op_ws, ml_ws);
  proj_fused_k<<<dim3(12, 64), 256, 0, stream>>>(op_ws, ml_ws, Wpt, bp, out);
}

// Round 13
// 94.989 us; speedup vs baseline: 1.5271x; 1.3427x over previous
//
#include <hip/hip_runtime.h>
#include <math.h>

namespace {

constexpr int E_  = 768;
constexpr int H_  = 12;
constexpr int DH_ = 64;
constexpr int T_  = 2048;
constexpr int B_  = 2;
constexpr int M_  = B_ * T_;  // 4096
constexpr int BH_ = B_ * H_;  // 24
constexpr int NSPLIT = 2;     // attention k-range split factor

typedef __attribute__((ext_vector_type(8))) short bf16x8;
typedef __attribute__((ext_vector_type(4))) float f32x4;

__device__ inline ushort f2bf(float f) {
  union { float f; unsigned u; } v; v.f = f;
  unsigned u = v.u + 0x7FFFu + ((v.u >> 16) & 1u);  // RNE
  return (ushort)(u >> 16);
}
__device__ inline float bf2f(ushort u) {
  union { unsigned u; float f; } v; v.u = (unsigned)u << 16; return v.f;
}

// async global->LDS, 16B per lane (wave-uniform LDS base, per-lane global src)
__device__ __forceinline__ void gl16(const ushort* g, ushort* l) {
  __builtin_amdgcn_global_load_lds(
      (const __attribute__((address_space(1))) unsigned int*)(g),
      (__attribute__((address_space(3))) unsigned int*)(l), 16, 0, 0);
}

// ---------------------------------------------------------------------------
// prep: blocks [0,1536) convert x f32->bf16; blocks [1536,2112) transpose W.
// ---------------------------------------------------------------------------
constexpr int NCONV = 1536;

__global__ __launch_bounds__(256) void prep_k(
    const float* __restrict__ x,
    const float* __restrict__ Wq, const float* __restrict__ Wk,
    const float* __restrict__ Wv, const float* __restrict__ Wp,
    ushort* __restrict__ xb, ushort* __restrict__ Wt, ushort* __restrict__ Wpt)
{
  __shared__ float tile[64][65];
  const int bid = blockIdx.x;
  const int tid = threadIdx.x;

  if (bid < NCONV) {
    const size_t i = ((size_t)bid * 256 + tid) * 8;
    float4 a = *(const float4*)(x + i);
    float4 b = *(const float4*)(x + i + 4);
    ushort o[8] = {f2bf(a.x), f2bf(a.y), f2bf(a.z), f2bf(a.w),
                   f2bf(b.x), f2bf(b.y), f2bf(b.z), f2bf(b.w)};
    *(bf16x8*)(xb + i) = *(bf16x8*)o;
    return;
  }

  const int wb = bid - NCONV;  // 0..575
  const int tr = tid >> 4, tc = tid & 15;
  const float* src; ushort* dst;
  int k0, n0, sN, dK;
  if (wb < 432) {
    const int mat = wb / 144, rem = wb % 144;
    const int h = rem / 12, ktile = rem % 12;
    const float* W = (mat == 0) ? Wq : (mat == 1) ? Wk : Wv;
    src = W + (size_t)h * E_ * DH_;
    dst = Wt + (size_t)(mat * H_ + h) * DH_ * E_;
    k0 = ktile * 64; n0 = 0; sN = DH_; dK = E_;
  } else {
    const int rem = wb - 432;
    src = Wp;
    dst = Wpt;
    k0 = (rem / 12) * 64; n0 = (rem % 12) * 64; sN = E_; dK = E_;
  }

#pragma unroll
  for (int rr = 0; rr < 64; rr += 16) {
    float4 v = *(const float4*)(src + (size_t)(k0 + tr + rr) * sN + n0 + tc * 4);
    tile[tr + rr][tc * 4 + 0] = v.x;
    tile[tr + rr][tc * 4 + 1] = v.y;
    tile[tr + rr][tc * 4 + 2] = v.z;
    tile[tr + rr][tc * 4 + 3] = v.w;
  }
  __syncthreads();
#pragma unroll
  for (int rr = 0; rr < 64; rr += 16) {
    const int n = tr + rr;
    ushort4 o;
    o.x = f2bf(tile[tc * 4 + 0][n]);
    o.y = f2bf(tile[tc * 4 + 1][n]);
    o.z = f2bf(tile[tc * 4 + 2][n]);
    o.w = f2bf(tile[tc * 4 + 3][n]);
    *(ushort4*)(dst + (size_t)(n0 + n) * dK + k0 + tc * 4) = o;
  }
}

// ---------------------------------------------------------------------------
// QKV GEMM: 128x64 tiles (R9-proven).
// ---------------------------------------------------------------------------
constexpr float QSCALE = 0.18033688f;  // 1/8 * log2(e)

__global__ __launch_bounds__(256) void qkv_fused_k(
    const ushort* __restrict__ xb, const ushort* __restrict__ Wt,
    ushort* __restrict__ q_ws, ushort* __restrict__ k_ws, ushort* __restrict__ vt_ws)
{
  __shared__ __align__(16) ushort lds[(128 + 64) * 64];  // As | Bs (24 KB)
  ushort* As = lds;
  ushort* Bs = lds + 128 * 64;

  const int seg = blockIdx.x;        // 0..35: (mat, head)
  const int m0  = blockIdx.y * 128;
  const ushort* Wh = Wt + (size_t)seg * DH_ * E_;

  const int tid  = threadIdx.x;
  const int w    = tid >> 6, l = tid & 63;
  const int lrow = l & 15, lk = l >> 4;
  const int r7   = lrow & 7;
  const int srow = l >> 3;
  const int sch  = (l & 7) ^ srow;

  f32x4 acc[2][4] = {};

  for (int k0 = 0; k0 < E_; k0 += 64) {
#pragma unroll
    for (int r = 0; r < 4; ++r) {
      const int base = r * 32 + w * 8;
      gl16(xb + (size_t)(m0 + base + srow) * E_ + k0 + sch * 8, &As[base * 64]);
      if (r < 2)
        gl16(Wh + (size_t)(base + srow) * E_ + k0 + sch * 8, &Bs[base * 64]);
    }
    __syncthreads();

#pragma unroll
    for (int kk = 0; kk < 2; ++kk) {
      const int cof = ((kk * 4 + lk) ^ r7) * 8;
      const bf16x8 a0 = *(const bf16x8*)&As[(w * 32 + lrow) * 64 + cof];
      const bf16x8 a1 = *(const bf16x8*)&As[(w * 32 + 16 + lrow) * 64 + cof];
#pragma unroll
      for (int nf = 0; nf < 4; ++nf) {
        const bf16x8 b = *(const bf16x8*)&Bs[(nf * 16 + lrow) * 64 + cof];
        acc[0][nf] = __builtin_amdgcn_mfma_f32_16x16x32_bf16(a0, b, acc[0][nf], 0, 0, 0);
        acc[1][nf] = __builtin_amdgcn_mfma_f32_16x16x32_bf16(a1, b, acc[1][nf], 0, 0, 0);
      }
    }
    __syncthreads();
  }

  const int b   = m0 >> 11;
  const int t0  = m0 & 2047;
  const int mat = seg / H_;
  const int h   = seg - mat * H_;
  const int bh  = b * H_ + h;

  if (mat != 2) {
    const float qs = (mat == 0) ? QSCALE : 1.0f;
    ushort* outw = (mat == 0) ? q_ws : k_ws;
#pragma unroll
    for (int mi = 0; mi < 2; ++mi)
#pragma unroll
      for (int i = 0; i < 4; ++i) {
        const int t = t0 + w * 32 + mi * 16 + lk * 4 + i;
        ushort* orow = outw + ((size_t)bh * T_ + t) * DH_;
#pragma unroll
        for (int nf = 0; nf < 4; ++nf)
          orow[nf * 16 + lrow] = f2bf(acc[mi][nf][i] * qs);
      }
  } else {
    ushort* Td = lds;  // [64][136]
    __syncthreads();
#pragma unroll
    for (int mi = 0; mi < 2; ++mi)
#pragma unroll
      for (int i = 0; i < 4; ++i) {
        const int tl = w * 32 + mi * 16 + lk * 4 + i;
#pragma unroll
        for (int nf = 0; nf < 4; ++nf)
          Td[(nf * 16 + lrow) * 136 + tl] = f2bf(acc[mi][nf][i]);
      }
    __syncthreads();
#pragma unroll
    for (int it = 0; it < 4; ++it) {
      const int c = tid + it * 256;
      const int d = c >> 4, sub = c & 15;
      *(bf16x8*)(vt_ws + ((size_t)bh * DH_ + d) * T_ + t0 + sub * 8) =
          *(const bf16x8*)&Td[d * 136 + sub * 8];
    }
  }
}

// ---------------------------------------------------------------------------
// Causal flash attention: R8's proven inner body (P through per-wave LDS,
// proven low-amplification epilogue) + R6's proven double-buffered K/V with
// ONE barrier per tile + split x2 (long-first ordering).
// LDS = 40 KB -> 4 blocks/CU.
// ---------------------------------------------------------------------------
__global__ __launch_bounds__(256) void attn_split_k(
    const ushort* __restrict__ q_ws, const ushort* __restrict__ k_ws,
    const ushort* __restrict__ vt_ws, ushort* __restrict__ op_ws,
    float2* __restrict__ ml_ws)
{
  __shared__ __align__(16) ushort Ks[2][64 * 64];  // K tile [s][e], swizzled
  __shared__ __align__(16) ushort Vt[2][64 * 64];  // V^T tile [d][s], swizzled
  __shared__ __align__(16) ushort Pl[4][16 * 64];  // per-wave P [q][s], swizzled

  const int qt = 31 - (int)blockIdx.y;
  const int bh = blockIdx.x;
  const int hz = blockIdx.z;               // 0..NSPLIT-1
  const int nt = qt + 1;
  const int klo = (hz * nt) / NSPLIT;
  const int khi = ((hz + 1) * nt) / NSPLIT;
  const int q0 = qt * 64;

  const ushort* Qb  = q_ws + (size_t)bh * T_ * DH_;
  const ushort* Kb  = k_ws + (size_t)bh * T_ * DH_;
  const ushort* VTb = vt_ws + (size_t)bh * DH_ * T_;

  const int tid  = threadIdx.x;
  const int w    = tid >> 6;
  const int l    = tid & 63;
  const int lrow = l & 15;
  const int lk   = l >> 4;
  const int r7   = lrow & 7;
  const int rr   = tid >> 3;       // staging rows rr, rr+32
  const int sub  = tid & 7;
  const int swc  = sub ^ (rr & 7);

  const int st0 = rr * 64 + swc * 8;
  const int st1 = (rr + 32) * 64 + swc * 8;

  int kof0[4], kof1[4];
#pragma unroll
  for (int ct = 0; ct < 4; ++ct) {
    kof0[ct] = (ct * 16 + lrow) * 64 + ((lk ^ r7) * 8);
    kof1[ct] = (ct * 16 + lrow) * 64 + (((lk + 4) ^ r7) * 8);
  }

  const ushort* Qrow = Qb + (size_t)(q0 + w * 16 + lrow) * DH_;
  const bf16x8 qa0 = *(const bf16x8*)(Qrow + lk * 8);
  const bf16x8 qa1 = *(const bf16x8*)(Qrow + lk * 8 + 32);
  const int qglob = q0 + w * 16 + lrow;

  float m_r = -INFINITY, l_r = 0.f;
  f32x4 oc[4] = {};

  ushort* Pw = &Pl[w][0];
  const int rd0 = lrow * 64 + ((lk ^ r7) * 8);
  const int rd1 = lrow * 64 + (((lk + 4) ^ r7) * 8);
  const int wrbase  = lrow * 128 + (lk & 1) * 8;
  const int wrchunk = (lk >> 1);

  if (klo < khi) {
    // prologue: tile klo -> regs -> buf 0
    bf16x8 kp0 = *(const bf16x8*)(Kb + (size_t)(klo * 64 + rr) * DH_ + sub * 8);
    bf16x8 kp1 = *(const bf16x8*)(Kb + (size_t)(klo * 64 + rr + 32) * DH_ + sub * 8);
    bf16x8 vp0 = *(const bf16x8*)(VTb + (size_t)rr * T_ + klo * 64 + sub * 8);
    bf16x8 vp1 = *(const bf16x8*)(VTb + (size_t)(rr + 32) * T_ + klo * 64 + sub * 8);
    *(bf16x8*)&Ks[0][st0] = kp0;
    *(bf16x8*)&Ks[0][st1] = kp1;
    *(bf16x8*)&Vt[0][st0] = vp0;
    *(bf16x8*)&Vt[0][st1] = vp1;
    __syncthreads();

    for (int kt = klo; kt < khi; ++kt) {
      const int s0  = kt * 64;
      const int cur = (kt - klo) & 1;

      // issue next tile's global loads early (hide under compute)
      if (kt + 1 < khi) {
        const int sn = s0 + 64;
        kp0 = *(const bf16x8*)(Kb + (size_t)(sn + rr) * DH_ + sub * 8);
        kp1 = *(const bf16x8*)(Kb + (size_t)(sn + rr + 32) * DH_ + sub * 8);
        vp0 = *(const bf16x8*)(VTb + (size_t)rr * T_ + sn + sub * 8);
        vp1 = *(const bf16x8*)(VTb + (size_t)(rr + 32) * T_ + sn + sub * 8);
      }

      // S^T = K Q^T : lane holds s = s0+ct*16+lk*4+i, q = lrow
      f32x4 st[4];
#pragma unroll
      for (int ct = 0; ct < 4; ++ct) {
        const bf16x8 kb0 = *(const bf16x8*)&Ks[cur][kof0[ct]];
        const bf16x8 kb1 = *(const bf16x8*)&Ks[cur][kof1[ct]];
        f32x4 z = {0.f, 0.f, 0.f, 0.f};
        z = __builtin_amdgcn_mfma_f32_16x16x32_bf16(kb0, qa0, z, 0, 0, 0);
        st[ct] = __builtin_amdgcn_mfma_f32_16x16x32_bf16(kb1, qa1, z, 0, 0, 0);
      }

      if (kt == qt) {  // diagonal tile only
#pragma unroll
        for (int ct = 0; ct < 4; ++ct)
#pragma unroll
          for (int i = 0; i < 4; ++i)
            if (s0 + ct * 16 + lk * 4 + i > qglob) st[ct][i] = -INFINITY;
      }

      float mc[4];
#pragma unroll
      for (int ct = 0; ct < 4; ++ct)
        mc[ct] = fmaxf(fmaxf(st[ct][0], st[ct][1]), fmaxf(st[ct][2], st[ct][3]));
      float mx = fmaxf(fmaxf(mc[0], mc[1]), fmaxf(mc[2], mc[3]));
      mx = fmaxf(mx, __shfl_xor(mx, 16));
      mx = fmaxf(mx, __shfl_xor(mx, 32));

      if (__any(mx > m_r + 8.f)) {
        const float mn   = fmaxf(m_r, mx);
        const float corr = exp2f(m_r - mn);
        m_r = mn;
        l_r *= corr;
#pragma unroll
        for (int i = 0; i < 4; ++i) {
          const float cr = __shfl(corr, lk * 4 + i);
#pragma unroll
          for (int ct = 0; ct < 4; ++ct) oc[ct][i] *= cr;
        }
      }

      float sc[4];
#pragma unroll
      for (int ct = 0; ct < 4; ++ct) {
#pragma unroll
        for (int i = 0; i < 4; ++i) st[ct][i] = exp2f(st[ct][i] - m_r);
        sc[ct] = (st[ct][0] + st[ct][1]) + (st[ct][2] + st[ct][3]);
      }
      float rs = (sc[0] + sc[1]) + (sc[2] + sc[3]);
      rs += __shfl_xor(rs, 16);
      rs += __shfl_xor(rs, 32);
      l_r += rs;

      // P^T -> per-wave LDS (packed bf16, swizzled 8B stores; no barrier)
#pragma unroll
      for (int ct = 0; ct < 4; ++ct) {
        unsigned lo, hi;
        asm("v_cvt_pk_bf16_f32 %0, %1, %2" : "=v"(lo) : "v"(st[ct][0]), "v"(st[ct][1]));
        asm("v_cvt_pk_bf16_f32 %0, %1, %2" : "=v"(hi) : "v"(st[ct][2]), "v"(st[ct][3]));
        uint2 pk; pk.x = lo; pk.y = hi;
        const int ch = ((ct * 2 + wrchunk) ^ r7);
        *(uint2*)((char*)Pw + wrbase + ch * 16) = pk;
      }

      const bf16x8 pa0 = *(const bf16x8*)(Pw + rd0);
      const bf16x8 pa1 = *(const bf16x8*)(Pw + rd1);

      // O += P V
#pragma unroll
      for (int ct = 0; ct < 4; ++ct) {
        const bf16x8 vb0 = *(const bf16x8*)&Vt[cur][kof0[ct]];
        const bf16x8 vb1 = *(const bf16x8*)&Vt[cur][kof1[ct]];
        oc[ct] = __builtin_amdgcn_mfma_f32_16x16x32_bf16(pa0, vb0, oc[ct], 0, 0, 0);
        oc[ct] = __builtin_amdgcn_mfma_f32_16x16x32_bf16(pa1, vb1, oc[ct], 0, 0, 0);
      }

      // commit next tile into the other buffer; single barrier per tile
      if (kt + 1 < khi) {
        const int nxt = cur ^ 1;
        *(bf16x8*)&Ks[nxt][st0] = kp0;
        *(bf16x8*)&Ks[nxt][st1] = kp1;
        *(bf16x8*)&Vt[nxt][st0] = vp0;
        *(bf16x8*)&Vt[nxt][st1] = vp1;
      }
      __syncthreads();
    }
  }

  // epilogue (R8-proven, low write amplification): unnormalized partial O
  const size_t pb = (size_t)(hz * BH_ + bh) * T_;
  if (lk == 0)
    ml_ws[pb + q0 + w * 16 + lrow] = make_float2(m_r, l_r);
#pragma unroll
  for (int i = 0; i < 4; ++i) {
    const int t = q0 + w * 16 + lk * 4 + i;
    ushort* orow = op_ws + (pb + t) * DH_;
#pragma unroll
    for (int ct = 0; ct < 4; ++ct)
      orow[ct * 16 + lrow] = f2bf(oc[ct][i]);
  }
}

// ---------------------------------------------------------------------------
// Out-proj GEMM with fused split-k combine (64x64 tiles, R9-proven).
// ---------------------------------------------------------------------------
__global__ __launch_bounds__(256) void proj_fused_k(
    const ushort* __restrict__ op_ws, const float2* __restrict__ ml_ws,
    const ushort* __restrict__ Wpt, const float* __restrict__ bp,
    float* __restrict__ out)
{
  __shared__ __align__(16) ushort lds[(64 + 64) * 64];  // As | Bs (16 KB)
  ushort* As = lds;
  ushort* Bs = lds + 64 * 64;

  const int n0 = blockIdx.x * 64;
  const int m0 = blockIdx.y * 64;
  const int b  = m0 >> 11;
  const int t0 = m0 & 2047;

  const int tid  = threadIdx.x;
  const int w    = tid >> 6, l = tid & 63;
  const int lrow = l & 15, lk = l >> 4;
  const int r7   = lrow & 7;
  const int srow = l >> 3;
  const int sch  = (l & 7) ^ srow;
  const int ar = tid >> 2;          // A-staging row 0..63
  const int cc = tid & 3;           // 16-elem chunk
  const int a7 = ar & 7;

  f32x4 acc[4] = {};

  for (int k0 = 0; k0 < E_; k0 += 64) {
    const int h  = k0 >> 6;
    const int bh = b * H_ + h;

#pragma unroll
    for (int r = 0; r < 2; ++r) {
      const int base = r * 32 + w * 8;
      gl16(Wpt + (size_t)(n0 + base + srow) * E_ + k0 + sch * 8, &Bs[base * 64]);
    }

    // A staging: combine NSPLIT partials in regs, swizzled ds_write
    {
      const int t = t0 + ar;
      size_t ix[NSPLIT];
      float2 ml[NSPLIT];
#pragma unroll
      for (int z = 0; z < NSPLIT; ++z) {
        ix[z] = ((size_t)(z * BH_ + bh) * T_ + t);
        ml[z] = ml_ws[ix[z]];
      }
      float m = ml[0].x;
#pragma unroll
      for (int z = 1; z < NSPLIT; ++z) m = fmaxf(m, ml[z].x);
      float f[NSPLIT];
      float den = 0.f;
#pragma unroll
      for (int z = 0; z < NSPLIT; ++z) {
        f[z] = exp2f(ml[z].x - m);
        den += f[z] * ml[z].y;
      }
      const float inv = 1.0f / den;
#pragma unroll
      for (int z = 0; z < NSPLIT; ++z) f[z] *= inv;

      float o[16] = {};
#pragma unroll
      for (int z = 0; z < NSPLIT; ++z) {
        const ushort* p = op_ws + ix[z] * DH_ + cc * 16;
        bf16x8 x0 = *(const bf16x8*)p;
        bf16x8 x1 = *(const bf16x8*)(p + 8);
#pragma unroll
        for (int j = 0; j < 8; ++j) {
          o[j]     += f[z] * bf2f((ushort)x0[j]);
          o[8 + j] += f[z] * bf2f((ushort)x1[j]);
        }
      }
      ushort ob[16];
#pragma unroll
      for (int j = 0; j < 16; ++j) ob[j] = f2bf(o[j]);
      *(bf16x8*)&As[ar * 64 + ((2 * cc) ^ a7) * 8]     = *(const bf16x8*)&ob[0];
      *(bf16x8*)&As[ar * 64 + ((2 * cc + 1) ^ a7) * 8] = *(const bf16x8*)&ob[8];
    }
    __syncthreads();

#pragma unroll
    for (int kk = 0; kk < 2; ++kk) {
      const int cof = ((kk * 4 + lk) ^ r7) * 8;
      const bf16x8 a = *(const bf16x8*)&As[(w * 16 + lrow) * 64 + cof];
#pragma unroll
      for (int nf = 0; nf < 4; ++nf) {
        const bf16x8 bb = *(const bf16x8*)&Bs[(nf * 16 + lrow) * 64 + cof];
        acc[nf] = __builtin_amdgcn_mfma_f32_16x16x32_bf16(a, bb, acc[nf], 0, 0, 0);
      }
    }
    __syncthreads();
  }

  float bias[4];
#pragma unroll
  for (int nf = 0; nf < 4; ++nf) bias[nf] = bp[n0 + nf * 16 + lrow];

#pragma unroll
  for (int i = 0; i < 4; ++i) {
    const int m = m0 + w * 16 + lk * 4 + i;
    float* orow = out + (size_t)m * E_ + n0;
#pragma unroll
    for (int nf = 0; nf < 4; ++nf)
      orow[nf * 16 + lrow] = acc[nf][i] + bias[nf];
  }
}

}  // namespace

extern "C" void kernel_launch(void* const* d_in, const int* in_sizes, int n_in,
                              void* d_out, int out_size, void* d_ws, size_t ws_size,
                              hipStream_t stream) {
  const float* x  = (const float*)d_in[0];
  const float* Wq = (const float*)d_in[1];
  const float* Wk = (const float*)d_in[2];
  const float* Wv = (const float*)d_in[3];
  const float* Wp = (const float*)d_in[4];
  const float* bp = (const float*)d_in[5];
  float* out = (float*)d_out;

  const size_t nx  = (size_t)M_ * E_;            // 3,145,728
  const size_t nwt = (size_t)3 * H_ * DH_ * E_;  // 1,769,472
  const size_t nwp = (size_t)E_ * E_;            // 589,824
  const size_t per = (size_t)BH_ * T_ * DH_;     // 3,145,728

  ushort* xb    = (ushort*)d_ws;
  ushort* Wt    = xb + nx;
  ushort* Wpt   = Wt + nwt;
  ushort* q_ws  = Wpt + nwp;
  ushort* k_ws  = q_ws + per;
  ushort* vt_ws = k_ws + per;     // [bh][d][t]
  ushort* op_ws = vt_ws + per;    // [NSPLIT][bh][t][64] partials
  float2* ml_ws = (float2*)(op_ws + NSPLIT * per);  // [NSPLIT][bh][t]

  prep_k<<<dim3(NCONV + 576), 256, 0, stream>>>(x, Wq, Wk, Wv, Wp, xb, Wt, Wpt);
  qkv_fused_k<<<dim3(36, 32), 256, 0, stream>>>(xb, Wt, q_ws, k_ws, vt_ws);
  attn_split_k<<<dim3(24, 32, NSPLIT), 256, 0, stream>>>(q_ws, k_ws, vt_ws, op_ws, ml_ws);
  proj_fused_k<<<dim3(12, 64), 256, 0, stream>>>(op_ws, ml_ws, Wpt, bp, out);
}

// Round 14
// 93.066 us; speedup vs baseline: 1.5586x; 1.0207x over previous
//
#include <hip/hip_runtime.h>
#include <math.h>

namespace {

constexpr int E_  = 768;
constexpr int H_  = 12;
constexpr int DH_ = 64;
constexpr int T_  = 2048;
constexpr int B_  = 2;
constexpr int M_  = B_ * T_;  // 4096
constexpr int BH_ = B_ * H_;  // 24
constexpr int NSPLIT = 2;     // attention k-range split factor

typedef __attribute__((ext_vector_type(8))) short bf16x8;
typedef __attribute__((ext_vector_type(4))) float f32x4;

__device__ inline ushort f2bf(float f) {
  union { float f; unsigned u; } v; v.f = f;
  unsigned u = v.u + 0x7FFFu + ((v.u >> 16) & 1u);  // RNE
  return (ushort)(u >> 16);
}
__device__ inline float bf2f(ushort u) {
  union { unsigned u; float f; } v; v.u = (unsigned)u << 16; return v.f;
}

// async global->LDS, 16B per lane (wave-uniform LDS base, per-lane global src)
__device__ __forceinline__ void gl16(const ushort* g, ushort* l) {
  __builtin_amdgcn_global_load_lds(
      (const __attribute__((address_space(1))) unsigned int*)(g),
      (__attribute__((address_space(3))) unsigned int*)(l), 16, 0, 0);
}

// ---------------------------------------------------------------------------
// prep: blocks [0,1536) convert x f32->bf16; blocks [1536,2112) transpose W.
// ---------------------------------------------------------------------------
constexpr int NCONV = 1536;

__global__ __launch_bounds__(256) void prep_k(
    const float* __restrict__ x,
    const float* __restrict__ Wq, const float* __restrict__ Wk,
    const float* __restrict__ Wv, const float* __restrict__ Wp,
    ushort* __restrict__ xb, ushort* __restrict__ Wt, ushort* __restrict__ Wpt)
{
  __shared__ float tile[64][65];
  const int bid = blockIdx.x;
  const int tid = threadIdx.x;

  if (bid < NCONV) {
    const size_t i = ((size_t)bid * 256 + tid) * 8;
    float4 a = *(const float4*)(x + i);
    float4 b = *(const float4*)(x + i + 4);
    ushort o[8] = {f2bf(a.x), f2bf(a.y), f2bf(a.z), f2bf(a.w),
                   f2bf(b.x), f2bf(b.y), f2bf(b.z), f2bf(b.w)};
    *(bf16x8*)(xb + i) = *(bf16x8*)o;
    return;
  }

  const int wb = bid - NCONV;  // 0..575
  const int tr = tid >> 4, tc = tid & 15;
  const float* src; ushort* dst;
  int k0, n0, sN, dK;
  if (wb < 432) {
    const int mat = wb / 144, rem = wb % 144;
    const int h = rem / 12, ktile = rem % 12;
    const float* W = (mat == 0) ? Wq : (mat == 1) ? Wk : Wv;
    src = W + (size_t)h * E_ * DH_;
    dst = Wt + (size_t)(mat * H_ + h) * DH_ * E_;
    k0 = ktile * 64; n0 = 0; sN = DH_; dK = E_;
  } else {
    const int rem = wb - 432;
    src = Wp;
    dst = Wpt;
    k0 = (rem / 12) * 64; n0 = (rem % 12) * 64; sN = E_; dK = E_;
  }

#pragma unroll
  for (int rr = 0; rr < 64; rr += 16) {
    float4 v = *(const float4*)(src + (size_t)(k0 + tr + rr) * sN + n0 + tc * 4);
    tile[tr + rr][tc * 4 + 0] = v.x;
    tile[tr + rr][tc * 4 + 1] = v.y;
    tile[tr + rr][tc * 4 + 2] = v.z;
    tile[tr + rr][tc * 4 + 3] = v.w;
  }
  __syncthreads();
#pragma unroll
  for (int rr = 0; rr < 64; rr += 16) {
    const int n = tr + rr;
    ushort4 o;
    o.x = f2bf(tile[tc * 4 + 0][n]);
    o.y = f2bf(tile[tc * 4 + 1][n]);
    o.z = f2bf(tile[tc * 4 + 2][n]);
    o.w = f2bf(tile[tc * 4 + 3][n]);
    *(ushort4*)(dst + (size_t)(n0 + n) * dK + k0 + tc * 4) = o;
  }
}

// ---------------------------------------------------------------------------
// QKV GEMM: 128x64 tiles (R9-proven, unchanged).
// ---------------------------------------------------------------------------
constexpr float QSCALE = 0.18033688f;  // 1/8 * log2(e)

__global__ __launch_bounds__(256) void qkv_fused_k(
    const ushort* __restrict__ xb, const ushort* __restrict__ Wt,
    ushort* __restrict__ q_ws, ushort* __restrict__ k_ws, ushort* __restrict__ vt_ws)
{
  __shared__ __align__(16) ushort lds[(128 + 64) * 64];  // As | Bs (24 KB)
  ushort* As = lds;
  ushort* Bs = lds + 128 * 64;

  const int seg = blockIdx.x;        // 0..35: (mat, head)
  const int m0  = blockIdx.y * 128;
  const ushort* Wh = Wt + (size_t)seg * DH_ * E_;

  const int tid  = threadIdx.x;
  const int w    = tid >> 6, l = tid & 63;
  const int lrow = l & 15, lk = l >> 4;
  const int r7   = lrow & 7;
  const int srow = l >> 3;
  const int sch  = (l & 7) ^ srow;

  f32x4 acc[2][4] = {};

  for (int k0 = 0; k0 < E_; k0 += 64) {
#pragma unroll
    for (int r = 0; r < 4; ++r) {
      const int base = r * 32 + w * 8;
      gl16(xb + (size_t)(m0 + base + srow) * E_ + k0 + sch * 8, &As[base * 64]);
      if (r < 2)
        gl16(Wh + (size_t)(base + srow) * E_ + k0 + sch * 8, &Bs[base * 64]);
    }
    __syncthreads();

#pragma unroll
    for (int kk = 0; kk < 2; ++kk) {
      const int cof = ((kk * 4 + lk) ^ r7) * 8;
      const bf16x8 a0 = *(const bf16x8*)&As[(w * 32 + lrow) * 64 + cof];
      const bf16x8 a1 = *(const bf16x8*)&As[(w * 32 + 16 + lrow) * 64 + cof];
#pragma unroll
      for (int nf = 0; nf < 4; ++nf) {
        const bf16x8 b = *(const bf16x8*)&Bs[(nf * 16 + lrow) * 64 + cof];
        acc[0][nf] = __builtin_amdgcn_mfma_f32_16x16x32_bf16(a0, b, acc[0][nf], 0, 0, 0);
        acc[1][nf] = __builtin_amdgcn_mfma_f32_16x16x32_bf16(a1, b, acc[1][nf], 0, 0, 0);
      }
    }
    __syncthreads();
  }

  const int b   = m0 >> 11;
  const int t0  = m0 & 2047;
  const int mat = seg / H_;
  const int h   = seg - mat * H_;
  const int bh  = b * H_ + h;

  if (mat != 2) {
    const float qs = (mat == 0) ? QSCALE : 1.0f;
    ushort* outw = (mat == 0) ? q_ws : k_ws;
#pragma unroll
    for (int mi = 0; mi < 2; ++mi)
#pragma unroll
      for (int i = 0; i < 4; ++i) {
        const int t = t0 + w * 32 + mi * 16 + lk * 4 + i;
        ushort* orow = outw + ((size_t)bh * T_ + t) * DH_;
#pragma unroll
        for (int nf = 0; nf < 4; ++nf)
          orow[nf * 16 + lrow] = f2bf(acc[mi][nf][i] * qs);
      }
  } else {
    ushort* Td = lds;  // [64][136]
    __syncthreads();
#pragma unroll
    for (int mi = 0; mi < 2; ++mi)
#pragma unroll
      for (int i = 0; i < 4; ++i) {
        const int tl = w * 32 + mi * 16 + lk * 4 + i;
#pragma unroll
        for (int nf = 0; nf < 4; ++nf)
          Td[(nf * 16 + lrow) * 136 + tl] = f2bf(acc[mi][nf][i]);
      }
    __syncthreads();
#pragma unroll
    for (int it = 0; it < 4; ++it) {
      const int c = tid + it * 256;
      const int d = c >> 4, sub = c & 15;
      *(bf16x8*)(vt_ws + ((size_t)bh * DH_ + d) * T_ + t0 + sub * 8) =
          *(const bf16x8*)&Td[d * 136 + sub * 8];
    }
  }
}

// ---------------------------------------------------------------------------
// Causal flash attention, split x2: R8-EXACT inner loop (single-buffered K/V,
// 2 barriers/tile, 24KB LDS -> 6 blocks/CU matching the 1536-block grid),
// reg-prefetch of next tile, per-wave swizzled P bounce, defer-max, exp2.
// ---------------------------------------------------------------------------
__global__ __launch_bounds__(256) void attn_split_k(
    const ushort* __restrict__ q_ws, const ushort* __restrict__ k_ws,
    const ushort* __restrict__ vt_ws, ushort* __restrict__ op_ws,
    float2* __restrict__ ml_ws)
{
  __shared__ __align__(16) ushort Ks[64 * 64];     // K tile [s][e], swizzled
  __shared__ __align__(16) ushort Vt[64 * 64];     // V^T tile [d][s], swizzled
  __shared__ __align__(16) ushort Pl[4][16 * 64];  // per-wave P [q][s], swizzled

  const int qt = 31 - (int)blockIdx.y;
  const int bh = blockIdx.x;
  const int hz = blockIdx.z;               // 0..NSPLIT-1
  const int nt = qt + 1;
  const int klo = (hz * nt) / NSPLIT;
  const int khi = ((hz + 1) * nt) / NSPLIT;
  const int q0 = qt * 64;

  const ushort* Qb  = q_ws + (size_t)bh * T_ * DH_;
  const ushort* Kb  = k_ws + (size_t)bh * T_ * DH_;
  const ushort* VTb = vt_ws + (size_t)bh * DH_ * T_;

  const int tid  = threadIdx.x;
  const int w    = tid >> 6;
  const int l    = tid & 63;
  const int lrow = l & 15;
  const int lk   = l >> 4;
  const int r7   = lrow & 7;
  const int rr   = tid >> 3;       // staging rows rr, rr+32
  const int sub  = tid & 7;
  const int swc  = sub ^ (rr & 7);

  const int st0 = rr * 64 + swc * 8;
  const int st1 = (rr + 32) * 64 + swc * 8;

  int kof0[4], kof1[4];
#pragma unroll
  for (int ct = 0; ct < 4; ++ct) {
    kof0[ct] = (ct * 16 + lrow) * 64 + ((lk ^ r7) * 8);
    kof1[ct] = (ct * 16 + lrow) * 64 + (((lk + 4) ^ r7) * 8);
  }

  const ushort* Qrow = Qb + (size_t)(q0 + w * 16 + lrow) * DH_;
  const bf16x8 qa0 = *(const bf16x8*)(Qrow + lk * 8);
  const bf16x8 qa1 = *(const bf16x8*)(Qrow + lk * 8 + 32);
  const int qglob = q0 + w * 16 + lrow;

  float m_r = -INFINITY, l_r = 0.f;
  f32x4 oc[4] = {};

  ushort* Pw = &Pl[w][0];
  const int rd0 = lrow * 64 + ((lk ^ r7) * 8);
  const int rd1 = lrow * 64 + (((lk + 4) ^ r7) * 8);
  const int wrbase  = lrow * 128 + (lk & 1) * 8;
  const int wrchunk = (lk >> 1);

  if (klo < khi) {
    // prologue: tile klo -> regs
    bf16x8 kp0 = *(const bf16x8*)(Kb + (size_t)(klo * 64 + rr) * DH_ + sub * 8);
    bf16x8 kp1 = *(const bf16x8*)(Kb + (size_t)(klo * 64 + rr + 32) * DH_ + sub * 8);
    bf16x8 vp0 = *(const bf16x8*)(VTb + (size_t)rr * T_ + klo * 64 + sub * 8);
    bf16x8 vp1 = *(const bf16x8*)(VTb + (size_t)(rr + 32) * T_ + klo * 64 + sub * 8);

    for (int kt = klo; kt < khi; ++kt) {
      const int s0 = kt * 64;

      // commit staged regs -> LDS; barrier opens compute phase
      *(bf16x8*)&Ks[st0] = kp0;
      *(bf16x8*)&Ks[st1] = kp1;
      *(bf16x8*)&Vt[st0] = vp0;
      *(bf16x8*)&Vt[st1] = vp1;
      __syncthreads();

      // issue next tile's global loads; latency hides under compute
      if (kt + 1 < khi) {
        const int sn = s0 + 64;
        kp0 = *(const bf16x8*)(Kb + (size_t)(sn + rr) * DH_ + sub * 8);
        kp1 = *(const bf16x8*)(Kb + (size_t)(sn + rr + 32) * DH_ + sub * 8);
        vp0 = *(const bf16x8*)(VTb + (size_t)rr * T_ + sn + sub * 8);
        vp1 = *(const bf16x8*)(VTb + (size_t)(rr + 32) * T_ + sn + sub * 8);
      }

      // S^T = K Q^T
      f32x4 st[4];
#pragma unroll
      for (int ct = 0; ct < 4; ++ct) {
        const bf16x8 kb0 = *(const bf16x8*)&Ks[kof0[ct]];
        const bf16x8 kb1 = *(const bf16x8*)&Ks[kof1[ct]];
        f32x4 z = {0.f, 0.f, 0.f, 0.f};
        z = __builtin_amdgcn_mfma_f32_16x16x32_bf16(kb0, qa0, z, 0, 0, 0);
        st[ct] = __builtin_amdgcn_mfma_f32_16x16x32_bf16(kb1, qa1, z, 0, 0, 0);
      }

      if (kt == qt) {  // diagonal tile only
#pragma unroll
        for (int ct = 0; ct < 4; ++ct)
#pragma unroll
          for (int i = 0; i < 4; ++i)
            if (s0 + ct * 16 + lk * 4 + i > qglob) st[ct][i] = -INFINITY;
      }

      float mc[4];
#pragma unroll
      for (int ct = 0; ct < 4; ++ct)
        mc[ct] = fmaxf(fmaxf(st[ct][0], st[ct][1]), fmaxf(st[ct][2], st[ct][3]));
      float mx = fmaxf(fmaxf(mc[0], mc[1]), fmaxf(mc[2], mc[3]));
      mx = fmaxf(mx, __shfl_xor(mx, 16));
      mx = fmaxf(mx, __shfl_xor(mx, 32));

      if (__any(mx > m_r + 8.f)) {
        const float mn   = fmaxf(m_r, mx);
        const float corr = exp2f(m_r - mn);
        m_r = mn;
        l_r *= corr;
#pragma unroll
        for (int i = 0; i < 4; ++i) {
          const float cr = __shfl(corr, lk * 4 + i);
#pragma unroll
          for (int ct = 0; ct < 4; ++ct) oc[ct][i] *= cr;
        }
      }

      float sc[4];
#pragma unroll
      for (int ct = 0; ct < 4; ++ct) {
#pragma unroll
        for (int i = 0; i < 4; ++i) st[ct][i] = exp2f(st[ct][i] - m_r);
        sc[ct] = (st[ct][0] + st[ct][1]) + (st[ct][2] + st[ct][3]);
      }
      float rs = (sc[0] + sc[1]) + (sc[2] + sc[3]);
      rs += __shfl_xor(rs, 16);
      rs += __shfl_xor(rs, 32);
      l_r += rs;

      // P^T -> per-wave LDS (packed bf16, swizzled 8B stores; no barrier)
#pragma unroll
      for (int ct = 0; ct < 4; ++ct) {
        unsigned lo, hi;
        asm("v_cvt_pk_bf16_f32 %0, %1, %2" : "=v"(lo) : "v"(st[ct][0]), "v"(st[ct][1]));
        asm("v_cvt_pk_bf16_f32 %0, %1, %2" : "=v"(hi) : "v"(st[ct][2]), "v"(st[ct][3]));
        uint2 pk; pk.x = lo; pk.y = hi;
        const int ch = ((ct * 2 + wrchunk) ^ r7);
        *(uint2*)((char*)Pw + wrbase + ch * 16) = pk;
      }

      const bf16x8 pa0 = *(const bf16x8*)(Pw + rd0);
      const bf16x8 pa1 = *(const bf16x8*)(Pw + rd1);

      // O += P V
#pragma unroll
      for (int ct = 0; ct < 4; ++ct) {
        const bf16x8 vb0 = *(const bf16x8*)&Vt[kof0[ct]];
        const bf16x8 vb1 = *(const bf16x8*)&Vt[kof1[ct]];
        oc[ct] = __builtin_amdgcn_mfma_f32_16x16x32_bf16(pa0, vb0, oc[ct], 0, 0, 0);
        oc[ct] = __builtin_amdgcn_mfma_f32_16x16x32_bf16(pa1, vb1, oc[ct], 0, 0, 0);
      }
      __syncthreads();  // all reads of Ks/Vt done before next commit
    }
  }

  // epilogue (R8-proven, low write amplification): unnormalized partial O
  const size_t pb = (size_t)(hz * BH_ + bh) * T_;
  if (lk == 0)
    ml_ws[pb + q0 + w * 16 + lrow] = make_float2(m_r, l_r);
#pragma unroll
  for (int i = 0; i < 4; ++i) {
    const int t = q0 + w * 16 + lk * 4 + i;
    ushort* orow = op_ws + (pb + t) * DH_;
#pragma unroll
    for (int ct = 0; ct < 4; ++ct)
      orow[ct * 16 + lrow] = f2bf(oc[ct][i]);
  }
}

// ---------------------------------------------------------------------------
// Out-proj GEMM with fused split-k combine (64x64 tiles, R9-proven).
// ---------------------------------------------------------------------------
__global__ __launch_bounds__(256) void proj_fused_k(
    const ushort* __restrict__ op_ws, const float2* __restrict__ ml_ws,
    const ushort* __restrict__ Wpt, const float* __restrict__ bp,
    float* __restrict__ out)
{
  __shared__ __align__(16) ushort lds[(64 + 64) * 64];  // As | Bs (16 KB)
  ushort* As = lds;
  ushort* Bs = lds + 64 * 64;

  const int n0 = blockIdx.x * 64;
  const int m0 = blockIdx.y * 64;
  const int b  = m0 >> 11;
  const int t0 = m0 & 2047;

  const int tid  = threadIdx.x;
  const int w    = tid >> 6, l = tid & 63;
  const int lrow = l & 15, lk = l >> 4;
  const int r7   = lrow & 7;
  const int srow = l >> 3;
  const int sch  = (l & 7) ^ srow;
  const int ar = tid >> 2;          // A-staging row 0..63
  const int cc = tid & 3;           // 16-elem chunk
  const int a7 = ar & 7;

  f32x4 acc[4] = {};

  for (int k0 = 0; k0 < E_; k0 += 64) {
    const int h  = k0 >> 6;
    const int bh = b * H_ + h;

#pragma unroll
    for (int r = 0; r < 2; ++r) {
      const int base = r * 32 + w * 8;
      gl16(Wpt + (size_t)(n0 + base + srow) * E_ + k0 + sch * 8, &Bs[base * 64]);
    }

    // A staging: combine NSPLIT partials in regs, swizzled ds_write
    {
      const int t = t0 + ar;
      size_t ix[NSPLIT];
      float2 ml[NSPLIT];
#pragma unroll
      for (int z = 0; z < NSPLIT; ++z) {
        ix[z] = ((size_t)(z * BH_ + bh) * T_ + t);
        ml[z] = ml_ws[ix[z]];
      }
      float m = ml[0].x;
#pragma unroll
      for (int z = 1; z < NSPLIT; ++z) m = fmaxf(m, ml[z].x);
      float f[NSPLIT];
      float den = 0.f;
#pragma unroll
      for (int z = 0; z < NSPLIT; ++z) {
        f[z] = exp2f(ml[z].x - m);
        den += f[z] * ml[z].y;
      }
      const float inv = 1.0f / den;
#pragma unroll
      for (int z = 0; z < NSPLIT; ++z) f[z] *= inv;

      float o[16] = {};
#pragma unroll
      for (int z = 0; z < NSPLIT; ++z) {
        const ushort* p = op_ws + ix[z] * DH_ + cc * 16;
        bf16x8 x0 = *(const bf16x8*)p;
        bf16x8 x1 = *(const bf16x8*)(p + 8);
#pragma unroll
        for (int j = 0; j < 8; ++j) {
          o[j]     += f[z] * bf2f((ushort)x0[j]);
          o[8 + j] += f[z] * bf2f((ushort)x1[j]);
        }
      }
      ushort ob[16];
#pragma unroll
      for (int j = 0; j < 16; ++j) ob[j] = f2bf(o[j]);
      *(bf16x8*)&As[ar * 64 + ((2 * cc) ^ a7) * 8]     = *(const bf16x8*)&ob[0];
      *(bf16x8*)&As[ar * 64 + ((2 * cc + 1) ^ a7) * 8] = *(const bf16x8*)&ob[8];
    }
    __syncthreads();

#pragma unroll
    for (int kk = 0; kk < 2; ++kk) {
      const int cof = ((kk * 4 + lk) ^ r7) * 8;
      const bf16x8 a = *(const bf16x8*)&As[(w * 16 + lrow) * 64 + cof];
#pragma unroll
      for (int nf = 0; nf < 4; ++nf) {
        const bf16x8 bb = *(const bf16x8*)&Bs[(nf * 16 + lrow) * 64 + cof];
        acc[nf] = __builtin_amdgcn_mfma_f32_16x16x32_bf16(a, bb, acc[nf], 0, 0, 0);
      }
    }
    __syncthreads();
  }

  float bias[4];
#pragma unroll
  for (int nf = 0; nf < 4; ++nf) bias[nf] = bp[n0 + nf * 16 + lrow];

#pragma unroll
  for (int i = 0; i < 4; ++i) {
    const int m = m0 + w * 16 + lk * 4 + i;
    float* orow = out + (size_t)m * E_ + n0;
#pragma unroll
    for (int nf = 0; nf < 4; ++nf)
      orow[nf * 16 + lrow] = acc[nf][i] + bias[nf];
  }
}

}  // namespace

extern "C" void kernel_launch(void* const* d_in, const int* in_sizes, int n_in,
                              void* d_out, int out_size, void* d_ws, size_t ws_size,
                              hipStream_t stream) {
  const float* x  = (const float*)d_in[0];
  const float* Wq = (const float*)d_in[1];
  const float* Wk = (const float*)d_in[2];
  const float* Wv = (const float*)d_in[3];
  const float* Wp = (const float*)d_in[4];
  const float* bp = (const float*)d_in[5];
  float* out = (float*)d_out;

  const size_t nx  = (size_t)M_ * E_;            // 3,145,728
  const size_t nwt = (size_t)3 * H_ * DH_ * E_;  // 1,769,472
  const size_t nwp = (size_t)E_ * E_;            // 589,824
  const size_t per = (size_t)BH_ * T_ * DH_;     // 3,145,728

  ushort* xb    = (ushort*)d_ws;
  ushort* Wt    = xb + nx;
  ushort* Wpt   = Wt + nwt;
  ushort* q_ws  = Wpt + nwp;
  ushort* k_ws  = q_ws + per;
  ushort* vt_ws = k_ws + per;     // [bh][d][t]
  ushort* op_ws = vt_ws + per;    // [NSPLIT][bh][t][64] partials
  float2* ml_ws = (float2*)(op_ws + NSPLIT * per);  // [NSPLIT][bh][t]

  prep_k<<<dim3(NCONV + 576), 256, 0, stream>>>(x, Wq, Wk, Wv, Wp, xb, Wt, Wpt);
  qkv_fused_k<<<dim3(36, 32), 256, 0, stream>>>(xb, Wt, q_ws, k_ws, vt_ws);
  attn_split_k<<<dim3(24, 32, NSPLIT), 256, 0, stream>>>(q_ws, k_ws, vt_ws, op_ws, ml_ws);
  proj_fused_k<<<dim3(12, 64), 256, 0, stream>>>(op_ws, ml_ws, Wpt, bp, out);
}

// Round 16
// 90.273 us; speedup vs baseline: 1.6069x; 1.0309x over previous
//
#include <hip/hip_runtime.h>
#include <math.h>

namespace {

constexpr int E_  = 768;
constexpr int H_  = 12;
constexpr int DH_ = 64;
constexpr int T_  = 2048;
constexpr int B_  = 2;
constexpr int M_  = B_ * T_;  // 4096
constexpr int BH_ = B_ * H_;  // 24
constexpr int NSPLIT = 2;     // attention k-range split factor

typedef __attribute__((ext_vector_type(8))) short bf16x8;
typedef __attribute__((ext_vector_type(4))) float f32x4;

__device__ inline ushort f2bf(float f) {
  union { float f; unsigned u; } v; v.f = f;
  unsigned u = v.u + 0x7FFFu + ((v.u >> 16) & 1u);  // RNE
  return (ushort)(u >> 16);
}
__device__ inline float bf2f(ushort u) {
  union { unsigned u; float f; } v; v.u = (unsigned)u << 16; return v.f;
}

// async global->LDS, 16B per lane (wave-uniform LDS base, per-lane global src)
__device__ __forceinline__ void gl16(const ushort* g, ushort* l) {
  __builtin_amdgcn_global_load_lds(
      (const __attribute__((address_space(1))) unsigned int*)(g),
      (__attribute__((address_space(3))) unsigned int*)(l), 16, 0, 0);
}

// ---------------------------------------------------------------------------
// prep: blocks [0,1536) convert x f32->bf16; blocks [1536,2112) transpose W.
// ---------------------------------------------------------------------------
constexpr int NCONV = 1536;

__global__ __launch_bounds__(256) void prep_k(
    const float* __restrict__ x,
    const float* __restrict__ Wq, const float* __restrict__ Wk,
    const float* __restrict__ Wv, const float* __restrict__ Wp,
    ushort* __restrict__ xb, ushort* __restrict__ Wt, ushort* __restrict__ Wpt)
{
  __shared__ float tile[64][65];
  const int bid = blockIdx.x;
  const int tid = threadIdx.x;

  if (bid < NCONV) {
    const size_t i = ((size_t)bid * 256 + tid) * 8;
    float4 a = *(const float4*)(x + i);
    float4 b = *(const float4*)(x + i + 4);
    ushort o[8] = {f2bf(a.x), f2bf(a.y), f2bf(a.z), f2bf(a.w),
                   f2bf(b.x), f2bf(b.y), f2bf(b.z), f2bf(b.w)};
    *(bf16x8*)(xb + i) = *(bf16x8*)o;
    return;
  }

  const int wb = bid - NCONV;  // 0..575
  const int tr = tid >> 4, tc = tid & 15;
  const float* src; ushort* dst;
  int k0, n0, sN, dK;
  if (wb < 432) {
    const int mat = wb / 144, rem = wb % 144;
    const int h = rem / 12, ktile = rem % 12;
    const float* W = (mat == 0) ? Wq : (mat == 1) ? Wk : Wv;
    src = W + (size_t)h * E_ * DH_;
    dst = Wt + (size_t)(mat * H_ + h) * DH_ * E_;
    k0 = ktile * 64; n0 = 0; sN = DH_; dK = E_;
  } else {
    const int rem = wb - 432;
    src = Wp;
    dst = Wpt;
    k0 = (rem / 12) * 64; n0 = (rem % 12) * 64; sN = E_; dK = E_;
  }

#pragma unroll
  for (int rr = 0; rr < 64; rr += 16) {
    float4 v = *(const float4*)(src + (size_t)(k0 + tr + rr) * sN + n0 + tc * 4);
    tile[tr + rr][tc * 4 + 0] = v.x;
    tile[tr + rr][tc * 4 + 1] = v.y;
    tile[tr + rr][tc * 4 + 2] = v.z;
    tile[tr + rr][tc * 4 + 3] = v.w;
  }
  __syncthreads();
#pragma unroll
  for (int rr = 0; rr < 64; rr += 16) {
    const int n = tr + rr;
    ushort4 o;
    o.x = f2bf(tile[tc * 4 + 0][n]);
    o.y = f2bf(tile[tc * 4 + 1][n]);
    o.z = f2bf(tile[tc * 4 + 2][n]);
    o.w = f2bf(tile[tc * 4 + 3][n]);
    *(ushort4*)(dst + (size_t)(n0 + n) * dK + k0 + tc * 4) = o;
  }
}

// ---------------------------------------------------------------------------
// QKV GEMM: 128x64 tiles (R9-proven, unchanged).
// ---------------------------------------------------------------------------
constexpr float QSCALE = 0.18033688f;  // 1/8 * log2(e)

__global__ __launch_bounds__(256) void qkv_fused_k(
    const ushort* __restrict__ xb, const ushort* __restrict__ Wt,
    ushort* __restrict__ q_ws, ushort* __restrict__ k_ws, ushort* __restrict__ vt_ws)
{
  __shared__ __align__(16) ushort lds[(128 + 64) * 64];  // As | Bs (24 KB)
  ushort* As = lds;
  ushort* Bs = lds + 128 * 64;

  const int seg = blockIdx.x;        // 0..35: (mat, head)
  const int m0  = blockIdx.y * 128;
  const ushort* Wh = Wt + (size_t)seg * DH_ * E_;

  const int tid  = threadIdx.x;
  const int w    = tid >> 6, l = tid & 63;
  const int lrow = l & 15, lk = l >> 4;
  const int r7   = lrow & 7;
  const int srow = l >> 3;
  const int sch  = (l & 7) ^ srow;

  f32x4 acc[2][4] = {};

  for (int k0 = 0; k0 < E_; k0 += 64) {
#pragma unroll
    for (int r = 0; r < 4; ++r) {
      const int base = r * 32 + w * 8;
      gl16(xb + (size_t)(m0 + base + srow) * E_ + k0 + sch * 8, &As[base * 64]);
      if (r < 2)
        gl16(Wh + (size_t)(base + srow) * E_ + k0 + sch * 8, &Bs[base * 64]);
    }
    __syncthreads();

#pragma unroll
    for (int kk = 0; kk < 2; ++kk) {
      const int cof = ((kk * 4 + lk) ^ r7) * 8;
      const bf16x8 a0 = *(const bf16x8*)&As[(w * 32 + lrow) * 64 + cof];
      const bf16x8 a1 = *(const bf16x8*)&As[(w * 32 + 16 + lrow) * 64 + cof];
#pragma unroll
      for (int nf = 0; nf < 4; ++nf) {
        const bf16x8 b = *(const bf16x8*)&Bs[(nf * 16 + lrow) * 64 + cof];
        acc[0][nf] = __builtin_amdgcn_mfma_f32_16x16x32_bf16(a0, b, acc[0][nf], 0, 0, 0);
        acc[1][nf] = __builtin_amdgcn_mfma_f32_16x16x32_bf16(a1, b, acc[1][nf], 0, 0, 0);
      }
    }
    __syncthreads();
  }

  const int b   = m0 >> 11;
  const int t0  = m0 & 2047;
  const int mat = seg / H_;
  const int h   = seg - mat * H_;
  const int bh  = b * H_ + h;

  if (mat != 2) {
    const float qs = (mat == 0) ? QSCALE : 1.0f;
    ushort* outw = (mat == 0) ? q_ws : k_ws;
#pragma unroll
    for (int mi = 0; mi < 2; ++mi)
#pragma unroll
      for (int i = 0; i < 4; ++i) {
        const int t = t0 + w * 32 + mi * 16 + lk * 4 + i;
        ushort* orow = outw + ((size_t)bh * T_ + t) * DH_;
#pragma unroll
        for (int nf = 0; nf < 4; ++nf)
          orow[nf * 16 + lrow] = f2bf(acc[mi][nf][i] * qs);
      }
  } else {
    ushort* Td = lds;  // [64][136]
    __syncthreads();
#pragma unroll
    for (int mi = 0; mi < 2; ++mi)
#pragma unroll
      for (int i = 0; i < 4; ++i) {
        const int tl = w * 32 + mi * 16 + lk * 4 + i;
#pragma unroll
        for (int nf = 0; nf < 4; ++nf)
          Td[(nf * 16 + lrow) * 136 + tl] = f2bf(acc[mi][nf][i]);
      }
    __syncthreads();
#pragma unroll
    for (int it = 0; it < 4; ++it) {
      const int c = tid + it * 256;
      const int d = c >> 4, sub = c & 15;
      *(bf16x8*)(vt_ws + ((size_t)bh * DH_ + d) * T_ + t0 + sub * 8) =
          *(const bf16x8*)&Td[d * 136 + sub * 8];
    }
  }
}

// ---------------------------------------------------------------------------
// Causal flash attention, split x2, QBLK=128 (512 threads, 8 waves).
// NaN fix vs R15: tiles with s0 > qwmin are FULLY masked for that wave
// (64-aligned tiles vs 16-aligned row groups) -> wave skips compute entirely
// (wave-uniform guard), avoiding exp2(-inf - -inf). Waves that compute
// nothing emit (m=-inf, l=0, oc=0); combine weight exp2(-inf - m) = 0 is
// exact. Staging and both barriers remain block-wide.
// ---------------------------------------------------------------------------
__global__ __launch_bounds__(512) void attn_split_k(
    const ushort* __restrict__ q_ws, const ushort* __restrict__ k_ws,
    const ushort* __restrict__ vt_ws, ushort* __restrict__ op_ws,
    float2* __restrict__ ml_ws)
{
  __shared__ __align__(16) ushort Ks[64 * 64];     // K tile [s][e], swizzled
  __shared__ __align__(16) ushort Vt[64 * 64];     // V^T tile [d][s], swizzled
  __shared__ __align__(16) ushort Pl[8][16 * 64];  // per-wave P [q][s], swizzled

  const int qt = 15 - (int)blockIdx.y;     // 128-row q-tile, long first
  const int bh = blockIdx.x;
  const int hz = blockIdx.z;               // 0..NSPLIT-1
  const int nt = 2 * qt + 2;               // 64-wide k-tiles in causal range
  const int klo = (hz * nt) / NSPLIT;
  const int khi = ((hz + 1) * nt) / NSPLIT;
  const int q0 = qt * 128;

  const ushort* Qb  = q_ws + (size_t)bh * T_ * DH_;
  const ushort* Kb  = k_ws + (size_t)bh * T_ * DH_;
  const ushort* VTb = vt_ws + (size_t)bh * DH_ * T_;

  const int tid  = threadIdx.x;
  const int w    = tid >> 6;        // 0..7
  const int l    = tid & 63;
  const int lrow = l & 15;
  const int lk   = l >> 4;
  const int r7   = lrow & 7;
  const int rr   = tid >> 3;        // staging row 0..63
  const int sub  = tid & 7;
  const int swc  = sub ^ (rr & 7);

  const int st0 = rr * 64 + swc * 8;

  int kof0[4], kof1[4];
#pragma unroll
  for (int ct = 0; ct < 4; ++ct) {
    kof0[ct] = (ct * 16 + lrow) * 64 + ((lk ^ r7) * 8);
    kof1[ct] = (ct * 16 + lrow) * 64 + (((lk + 4) ^ r7) * 8);
  }

  const ushort* Qrow = Qb + (size_t)(q0 + w * 16 + lrow) * DH_;
  const bf16x8 qa0 = *(const bf16x8*)(Qrow + lk * 8);
  const bf16x8 qa1 = *(const bf16x8*)(Qrow + lk * 8 + 32);
  const int qglob = q0 + w * 16 + lrow;
  const int qwmin = q0 + w * 16;

  float m_r = -INFINITY, l_r = 0.f;
  f32x4 oc[4] = {};

  ushort* Pw = &Pl[w][0];
  const int rd0 = lrow * 64 + ((lk ^ r7) * 8);
  const int rd1 = lrow * 64 + (((lk + 4) ^ r7) * 8);
  const int wrbase  = lrow * 128 + (lk & 1) * 8;
  const int wrchunk = (lk >> 1);

  {
    // prologue: tile klo -> regs
    bf16x8 kp = *(const bf16x8*)(Kb + (size_t)(klo * 64 + rr) * DH_ + sub * 8);
    bf16x8 vp = *(const bf16x8*)(VTb + (size_t)rr * T_ + klo * 64 + sub * 8);

    for (int kt = klo; kt < khi; ++kt) {
      const int s0 = kt * 64;

      // commit staged regs -> LDS; barrier opens compute phase
      *(bf16x8*)&Ks[st0] = kp;
      *(bf16x8*)&Vt[st0] = vp;
      __syncthreads();

      // issue next tile's global loads; latency hides under compute
      if (kt + 1 < khi) {
        const int sn = s0 + 64;
        kp = *(const bf16x8*)(Kb + (size_t)(sn + rr) * DH_ + sub * 8);
        vp = *(const bf16x8*)(VTb + (size_t)rr * T_ + sn + sub * 8);
      }

      // wave-uniform: s0 > qwmin => tile fully masked for this wave -> skip
      if (s0 <= qwmin) {
        // S^T = K Q^T
        f32x4 st[4];
#pragma unroll
        for (int ct = 0; ct < 4; ++ct) {
          const bf16x8 kb0 = *(const bf16x8*)&Ks[kof0[ct]];
          const bf16x8 kb1 = *(const bf16x8*)&Ks[kof1[ct]];
          f32x4 z = {0.f, 0.f, 0.f, 0.f};
          z = __builtin_amdgcn_mfma_f32_16x16x32_bf16(kb0, qa0, z, 0, 0, 0);
          st[ct] = __builtin_amdgcn_mfma_f32_16x16x32_bf16(kb1, qa1, z, 0, 0, 0);
        }

        if (s0 + 63 > qwmin) {  // partial (diagonal) tile for this wave
#pragma unroll
          for (int ct = 0; ct < 4; ++ct)
#pragma unroll
            for (int i = 0; i < 4; ++i)
              if (s0 + ct * 16 + lk * 4 + i > qglob) st[ct][i] = -INFINITY;
        }

        float mc[4];
#pragma unroll
        for (int ct = 0; ct < 4; ++ct)
          mc[ct] = fmaxf(fmaxf(st[ct][0], st[ct][1]), fmaxf(st[ct][2], st[ct][3]));
        float mx = fmaxf(fmaxf(mc[0], mc[1]), fmaxf(mc[2], mc[3]));
        mx = fmaxf(mx, __shfl_xor(mx, 16));
        mx = fmaxf(mx, __shfl_xor(mx, 32));

        if (__any(mx > m_r + 8.f)) {
          const float mn   = fmaxf(m_r, mx);
          const float corr = exp2f(m_r - mn);
          m_r = mn;
          l_r *= corr;
#pragma unroll
          for (int i = 0; i < 4; ++i) {
            const float cr = __shfl(corr, lk * 4 + i);
#pragma unroll
            for (int ct = 0; ct < 4; ++ct) oc[ct][i] *= cr;
          }
        }

        float sc[4];
#pragma unroll
        for (int ct = 0; ct < 4; ++ct) {
#pragma unroll
          for (int i = 0; i < 4; ++i) st[ct][i] = exp2f(st[ct][i] - m_r);
          sc[ct] = (st[ct][0] + st[ct][1]) + (st[ct][2] + st[ct][3]);
        }
        float rs = (sc[0] + sc[1]) + (sc[2] + sc[3]);
        rs += __shfl_xor(rs, 16);
        rs += __shfl_xor(rs, 32);
        l_r += rs;

        // P^T -> per-wave LDS (packed bf16, swizzled 8B stores; no barrier)
#pragma unroll
        for (int ct = 0; ct < 4; ++ct) {
          unsigned lo, hi;
          asm("v_cvt_pk_bf16_f32 %0, %1, %2" : "=v"(lo) : "v"(st[ct][0]), "v"(st[ct][1]));
          asm("v_cvt_pk_bf16_f32 %0, %1, %2" : "=v"(hi) : "v"(st[ct][2]), "v"(st[ct][3]));
          uint2 pk; pk.x = lo; pk.y = hi;
          const int ch = ((ct * 2 + wrchunk) ^ r7);
          *(uint2*)((char*)Pw + wrbase + ch * 16) = pk;
        }

        const bf16x8 pa0 = *(const bf16x8*)(Pw + rd0);
        const bf16x8 pa1 = *(const bf16x8*)(Pw + rd1);

        // O += P V
#pragma unroll
        for (int ct = 0; ct < 4; ++ct) {
          const bf16x8 vb0 = *(const bf16x8*)&Vt[kof0[ct]];
          const bf16x8 vb1 = *(const bf16x8*)&Vt[kof1[ct]];
          oc[ct] = __builtin_amdgcn_mfma_f32_16x16x32_bf16(pa0, vb0, oc[ct], 0, 0, 0);
          oc[ct] = __builtin_amdgcn_mfma_f32_16x16x32_bf16(pa1, vb1, oc[ct], 0, 0, 0);
        }
      }
      __syncthreads();  // all reads of Ks/Vt done before next commit
    }
  }

  // epilogue (R8-proven): unnormalized partial O + per-row (m,l)
  const size_t pb = (size_t)(hz * BH_ + bh) * T_;
  if (lk == 0)
    ml_ws[pb + q0 + w * 16 + lrow] = make_float2(m_r, l_r);
#pragma unroll
  for (int i = 0; i < 4; ++i) {
    const int t = q0 + w * 16 + lk * 4 + i;
    ushort* orow = op_ws + (pb + t) * DH_;
#pragma unroll
    for (int ct = 0; ct < 4; ++ct)
      orow[ct * 16 + lrow] = f2bf(oc[ct][i]);
  }
}

// ---------------------------------------------------------------------------
// Out-proj GEMM with fused split-k combine (64x64 tiles, R9-proven).
// Handles (m=-inf, l=0) padding splits exactly: exp2(-inf - m) = 0.
// ---------------------------------------------------------------------------
__global__ __launch_bounds__(256) void proj_fused_k(
    const ushort* __restrict__ op_ws, const float2* __restrict__ ml_ws,
    const ushort* __restrict__ Wpt, const float* __restrict__ bp,
    float* __restrict__ out)
{
  __shared__ __align__(16) ushort lds[(64 + 64) * 64];  // As | Bs (16 KB)
  ushort* As = lds;
  ushort* Bs = lds + 64 * 64;

  const int n0 = blockIdx.x * 64;
  const int m0 = blockIdx.y * 64;
  const int b  = m0 >> 11;
  const int t0 = m0 & 2047;

  const int tid  = threadIdx.x;
  const int w    = tid >> 6, l = tid & 63;
  const int lrow = l & 15, lk = l >> 4;
  const int r7   = lrow & 7;
  const int srow = l >> 3;
  const int sch  = (l & 7) ^ srow;
  const int ar = tid >> 2;          // A-staging row 0..63
  const int cc = tid & 3;           // 16-elem chunk
  const int a7 = ar & 7;

  f32x4 acc[4] = {};

  for (int k0 = 0; k0 < E_; k0 += 64) {
    const int h  = k0 >> 6;
    const int bh = b * H_ + h;

#pragma unroll
    for (int r = 0; r < 2; ++r) {
      const int base = r * 32 + w * 8;
      gl16(Wpt + (size_t)(n0 + base + srow) * E_ + k0 + sch * 8, &Bs[base * 64]);
    }

    // A staging: combine NSPLIT partials in regs, swizzled ds_write
    {
      const int t = t0 + ar;
      size_t ix[NSPLIT];
      float2 ml[NSPLIT];
#pragma unroll
      for (int z = 0; z < NSPLIT; ++z) {
        ix[z] = ((size_t)(z * BH_ + bh) * T_ + t);
        ml[z] = ml_ws[ix[z]];
      }
      float m = ml[0].x;
#pragma unroll
      for (int z = 1; z < NSPLIT; ++z) m = fmaxf(m, ml[z].x);
      float f[NSPLIT];
      float den = 0.f;
#pragma unroll
      for (int z = 0; z < NSPLIT; ++z) {
        f[z] = exp2f(ml[z].x - m);
        den += f[z] * ml[z].y;
      }
      const float inv = 1.0f / den;
#pragma unroll
      for (int z = 0; z < NSPLIT; ++z) f[z] *= inv;

      float o[16] = {};
#pragma unroll
      for (int z = 0; z < NSPLIT; ++z) {
        const ushort* p = op_ws + ix[z] * DH_ + cc * 16;
        bf16x8 x0 = *(const bf16x8*)p;
        bf16x8 x1 = *(const bf16x8*)(p + 8);
#pragma unroll
        for (int j = 0; j < 8; ++j) {
          o[j]     += f[z] * bf2f((ushort)x0[j]);
          o[8 + j] += f[z] * bf2f((ushort)x1[j]);
        }
      }
      ushort ob[16];
#pragma unroll
      for (int j = 0; j < 16; ++j) ob[j] = f2bf(o[j]);
      *(bf16x8*)&As[ar * 64 + ((2 * cc) ^ a7) * 8]     = *(const bf16x8*)&ob[0];
      *(bf16x8*)&As[ar * 64 + ((2 * cc + 1) ^ a7) * 8] = *(const bf16x8*)&ob[8];
    }
    __syncthreads();

#pragma unroll
    for (int kk = 0; kk < 2; ++kk) {
      const int cof = ((kk * 4 + lk) ^ r7) * 8;
      const bf16x8 a = *(const bf16x8*)&As[(w * 16 + lrow) * 64 + cof];
#pragma unroll
      for (int nf = 0; nf < 4; ++nf) {
        const bf16x8 bb = *(const bf16x8*)&Bs[(nf * 16 + lrow) * 64 + cof];
        acc[nf] = __builtin_amdgcn_mfma_f32_16x16x32_bf16(a, bb, acc[nf], 0, 0, 0);
      }
    }
    __syncthreads();
  }

  float bias[4];
#pragma unroll
  for (int nf = 0; nf < 4; ++nf) bias[nf] = bp[n0 + nf * 16 + lrow];

#pragma unroll
  for (int i = 0; i < 4; ++i) {
    const int m = m0 + w * 16 + lk * 4 + i;
    float* orow = out + (size_t)m * E_ + n0;
#pragma unroll
    for (int nf = 0; nf < 4; ++nf)
      orow[nf * 16 + lrow] = acc[nf][i] + bias[nf];
  }
}

}  // namespace

extern "C" void kernel_launch(void* const* d_in, const int* in_sizes, int n_in,
                              void* d_out, int out_size, void* d_ws, size_t ws_size,
                              hipStream_t stream) {
  const float* x  = (const float*)d_in[0];
  const float* Wq = (const float*)d_in[1];
  const float* Wk = (const float*)d_in[2];
  const float* Wv = (const float*)d_in[3];
  const float* Wp = (const float*)d_in[4];
  const float* bp = (const float*)d_in[5];
  float* out = (float*)d_out;

  const size_t nx  = (size_t)M_ * E_;            // 3,145,728
  const size_t nwt = (size_t)3 * H_ * DH_ * E_;  // 1,769,472
  const size_t nwp = (size_t)E_ * E_;            // 589,824
  const size_t per = (size_t)BH_ * T_ * DH_;     // 3,145,728

  ushort* xb    = (ushort*)d_ws;
  ushort* Wt    = xb + nx;
  ushort* Wpt   = Wt + nwt;
  ushort* q_ws  = Wpt + nwp;
  ushort* k_ws  = q_ws + per;
  ushort* vt_ws = k_ws + per;     // [bh][d][t]
  ushort* op_ws = vt_ws + per;    // [NSPLIT][bh][t][64] partials
  float2* ml_ws = (float2*)(op_ws + NSPLIT * per);  // [NSPLIT][bh][t]

  prep_k<<<dim3(NCONV + 576), 256, 0, stream>>>(x, Wq, Wk, Wv, Wp, xb, Wt, Wpt);
  qkv_fused_k<<<dim3(36, 32), 256, 0, stream>>>(xb, Wt, q_ws, k_ws, vt_ws);
  attn_split_k<<<dim3(24, 16, NSPLIT), 512, 0, stream>>>(q_ws, k_ws, vt_ws, op_ws, ml_ws);
  proj_fused_k<<<dim3(12, 64), 256, 0, stream>>>(op_ws, ml_ws, Wpt, bp, out);
}